// Round 7
// baseline (1110.760 us; speedup 1.0000x reference)
//
#include <hip/hip_runtime.h>

// Flow_49160195670664: Dopri5 fixed-step integration of dx/dt = A x + B u(t),
// T=32768, N=256, NI=NO=32, dt=1, Hermite-interpolated stage inputs.
// Linear system => x_{n+1} = R x_n + v_n with constant R.
// v4: 4-level blocked parallel scan 8 x 8 x 8 x 64.
// v5: y register-tiled 4x4 (was LDS-throughput-bound).
// v6: launch-graph collapse (r6 analysis: ~130us of the 342 was serial launch
// gaps at ~6-7us x 14 launches). The whole scan phase (3 powers, 3 reduces,
// top, 3 expands, y) is ONE kernel with a hand-rolled grid barrier: 256 blocks
// x 1024 thr x 112KB LDS = exactly 1 block/CU, all co-resident. Independent
// phases overlap: pow8 || reduce0(240u), reduce0-tail || pow64, reduce1 ||
// pow512. build_wtap folded into the drive GEMM (taps from u on the fly).
// 14 launches -> 4.

#define TPTS 32768

typedef __attribute__((ext_vector_type(8))) short short8;
typedef __attribute__((ext_vector_type(4))) float float4v;
typedef unsigned short ushort_t;

__device__ __forceinline__ ushort_t bf16_hi(float f) {
  unsigned u = __builtin_bit_cast(unsigned, f);
  unsigned r = (u + 0x7FFFu + ((u >> 16) & 1u)) >> 16;
  return (ushort_t)r;
}
__device__ __forceinline__ float bf16_f(ushort_t h) {
  unsigned u = ((unsigned)h) << 16;
  return __builtin_bit_cast(float, u);
}

// ---------------------------------------------------------------------------
// Grid barrier: generation-counting, agent-scope atomics. Requires all blocks
// co-resident (mega: 256 blocks, 1/CU by LDS). Works from any initial gen
// (rocprof replay safe); cnt must start 0 (zeroed by transpose_at; self-resets).
__device__ __forceinline__ void grid_bar(unsigned* cnt, unsigned* gen) {
  __syncthreads();
  if (threadIdx.x == 0) {
    __threadfence();
    unsigned g = __hip_atomic_load(gen, __ATOMIC_RELAXED, __HIP_MEMORY_SCOPE_AGENT);
    unsigned a = __hip_atomic_fetch_add(cnt, 1u, __ATOMIC_ACQ_REL, __HIP_MEMORY_SCOPE_AGENT);
    if (a == 255u) {
      __hip_atomic_store(cnt, 0u, __ATOMIC_RELAXED, __HIP_MEMORY_SCOPE_AGENT);
      __hip_atomic_store(gen, g + 1u, __ATOMIC_RELEASE, __HIP_MEMORY_SCOPE_AGENT);
    } else {
      while (__hip_atomic_load(gen, __ATOMIC_ACQUIRE, __HIP_MEMORY_SCOPE_AGENT) == g)
        __builtin_amdgcn_s_sleep(2);
    }
    __threadfence();
  }
  __syncthreads();
}

// ---------------------------------------------------------------------------
// MFMA chain body (device fn). 1024 thr = 16 waves; wave w owns output cols
// [16w,16w+16) as ONE N-tile of mfma_f32_16x16x32_bf16; 16 chains = M-dim.
// bf16 hi/lo split (x*R ~ xh*Rh + xl*Rh + xh*Rl, fp32 acc), 3 independent
// accumulators. V-drive register-prefetched one step ahead. blk is LOGICAL.
// MODE 0: power  (CLEN steps, x0 = I cols; Out = M^CLEN row-major fp32 + h/l)
// MODE 1: reduce (x0 = V row0 of chain, drive rows 1..CLEN-1; Out[chain]=final)
// MODE 2: expand (x0 = X0[chain], drive rows 0..CLEN-2; Out rows chain*CLEN+j)
// Arena layout: xh @0 (16KB), xl @16K (16KB), hist @32K (80KB) = 112KB.
template <int MODE, int CLEN>
__device__ __forceinline__ void chain_body(char* arena, const ushort_t* Mh, const ushort_t* Ml,
                                           const float* X0, const float* V,
                                           float* Out, ushort_t* OutH, ushort_t* OutL, int blk) {
  constexpr int STEPS = (MODE == 0) ? CLEN : CLEN - 1;
  int t = threadIdx.x;
  int w = t >> 6, l = t & 63;   // w 0..15
  int q = l >> 4, c16 = l & 15;
  int n0 = w * 16;
  ushort_t (*xh)[32][16][8] = reinterpret_cast<ushort_t(*)[32][16][8]>(arena);
  ushort_t (*xl)[32][16][8] = reinterpret_cast<ushort_t(*)[32][16][8]>(arena + 16384);
  float (*hist)[16][256] = reinterpret_cast<float(*)[16][256]>(arena + 32768);
  // B-frags: B[k][n] = M[n][k]; lane holds B[kt*32+q*8+j][n0+c16], j=0..7
  short8 bh[8], bl[8];
#pragma unroll
  for (int kt = 0; kt < 8; kt++) {
    size_t offs = (size_t)(n0 + c16) * 256 + kt * 32 + q * 8;
    bh[kt] = *(const short8*)(Mh + offs);
    bl[kt] = *(const short8*)(Ml + offs);
  }
  // initial x (and row-0 store for MODE 2): 1024 float4, one per thread
  {
    int e = t;
    int c = e >> 6, qq = (e & 63) * 4;
    int cg = blk * 16 + c;
    float4 v4;
    if (MODE == 0) {
      v4 = make_float4(qq == cg ? 1.f : 0.f, qq + 1 == cg ? 1.f : 0.f,
                       qq + 2 == cg ? 1.f : 0.f, qq + 3 == cg ? 1.f : 0.f);
    } else if (MODE == 1) {
      v4 = *(const float4*)(V + (size_t)cg * CLEN * 256 + qq);
    } else {
      v4 = *(const float4*)(X0 + (size_t)cg * 256 + qq);
      *(float4*)(Out + ((size_t)cg * CLEN) * 256 + qq) = v4;
    }
    float vals[4] = {v4.x, v4.y, v4.z, v4.w};
#pragma unroll
    for (int i = 0; i < 4; i++) {
      int n = qq + i;
      ushort_t h = bf16_hi(vals[i]);
      xh[0][n >> 3][c][n & 7] = h;
      xl[0][n >> 3][c][n & 7] = bf16_hi(vals[i] - bf16_f(h));
    }
  }
  // per-lane drive prefetch for step 1 (element r: chain q*4+r, col n0+c16)
  float vnext[4];
  if (MODE != 0) {
#pragma unroll
    for (int r = 0; r < 4; r++) {
      int cg = blk * 16 + q * 4 + r;
      int drow = (MODE == 1) ? 1 : 0;
      vnext[r] = V[((size_t)cg * CLEN + drow) * 256 + n0 + c16];
    }
  }
  __syncthreads();
  for (int s = 1; s <= STEPS; s++) {
    int cur = (s - 1) & 1, nxt = s & 1;
    // MODE 2: flush rows s-4..s-1 (slots row%5) — mod-5 disjoint vs writes
    if (MODE == 2 && s >= 5 && ((s - 1) & 3) == 0) {
      int rbase = s - 4;
      for (int e = t; e < 4096; e += 1024) {
        int slot = e >> 10;
        int rem = e & 1023;
        int c = rem >> 6, qq = (rem & 63) * 4;
        int row = rbase + slot;
        int cg = blk * 16 + c;
        *(float4*)(Out + ((size_t)cg * CLEN + row) * 256 + qq) = *(const float4*)&hist[row % 5][c][qq];
      }
    }
    // drive: consume prefetched, issue next step's loads (hidden under MFMAs)
    float vc[4];
    if (MODE != 0) {
#pragma unroll
      for (int i2 = 0; i2 < 4; i2++) vc[i2] = vnext[i2];
      if (s < STEPS) {
        int drow = (MODE == 1) ? (s + 1) : s;
#pragma unroll
        for (int r = 0; r < 4; r++)
          vnext[r] = V[((size_t)(blk * 16 + q * 4 + r) * CLEN + drow) * 256 + n0 + c16];
      }
    }
    // pin frags: rw asm operand => value must live in VGPRs, reload illegal
#pragma unroll
    for (int kt = 0; kt < 8; kt++) {
      asm volatile("" : "+v"(bh[kt]));
      asm volatile("" : "+v"(bl[kt]));
    }
    float4v aH = {0.f, 0.f, 0.f, 0.f};
    float4v aL = {0.f, 0.f, 0.f, 0.f};
    float4v aC = {0.f, 0.f, 0.f, 0.f};
#pragma unroll
    for (int kt = 0; kt < 8; kt++) {
      short8 ah = *(const short8*)&(*xh)[0][0][0];  // placeholder to keep types honest
      (void)ah;
      short8 ah2 = *(const short8*)&xh[cur][kt * 4 + q][c16][0];
      short8 al2 = *(const short8*)&xl[cur][kt * 4 + q][c16][0];
      aH = __builtin_amdgcn_mfma_f32_16x16x32_bf16(ah2, bh[kt], aH, 0, 0, 0);
      aL = __builtin_amdgcn_mfma_f32_16x16x32_bf16(al2, bh[kt], aL, 0, 0, 0);
      aC = __builtin_amdgcn_mfma_f32_16x16x32_bf16(ah2, bl[kt], aC, 0, 0, 0);
    }
    // epilogue: C/D layout chain=(q*4+r), col=c16 (m89-verified)
#pragma unroll
    for (int r = 0; r < 4; r++) {
      int c = q * 4 + r;
      int n = n0 + c16;
      float val = aH[r] + aL[r] + aC[r];
      if (MODE != 0) val += vc[r];
      int cg = blk * 16 + c;
      if (MODE == 2) hist[s % 5][c][n] = val;
      if (MODE == 1 && s == STEPS) Out[(size_t)cg * 256 + n] = val;
      if (MODE == 0 && s == STEPS) {
        ushort_t h2 = bf16_hi(val);
        Out[(size_t)n * 256 + cg] = val;
        OutH[(size_t)n * 256 + cg] = h2;
        OutL[(size_t)n * 256 + cg] = bf16_hi(val - bf16_f(h2));
      }
      ushort_t h = bf16_hi(val);
      xh[nxt][n >> 3][c][n & 7] = h;
      xl[nxt][n >> 3][c][n & 7] = bf16_hi(val - bf16_f(h));
    }
    __syncthreads();
  }
  if (MODE == 2) {   // final rows STEPS-2..STEPS
    for (int e = t; e < 3072; e += 1024) {
      int slot = e >> 10;
      int rem = e & 1023;
      int c = rem >> 6, qq = (rem & 63) * 4;
      int row = (STEPS - 2) + slot;
      int cg = blk * 16 + c;
      *(float4*)(Out + ((size_t)cg * CLEN + row) * 256 + qq) = *(const float4*)&hist[row % 5][c][qq];
    }
  }
}

// ---------------------------------------------------------------------------
// Mega scan kernel: powers + reduces + top + expands + y in one launch.
// 256 blocks x 1024 thr, 112KB arena -> 1 block/CU, all co-resident.
__global__ __launch_bounds__(1024, 4) void mega_scan(
    const ushort_t* Rh, const ushort_t* Rl,
    ushort_t* R8h, ushort_t* R8l, ushort_t* R64h, ushort_t* R64l,
    float* R512fp, ushort_t* R512h, ushort_t* R512l, float* PowFp,
    const float* V0, float* V1, float* V2, float* V3,
    const float* x0, float* X3, float* X2, float* X1,
    float* xout, const float* u, const float* Cm, const float* Dm, float* yout,
    unsigned* bar) {
  __shared__ __attribute__((aligned(16))) char arena[114688];
  int blk = blockIdx.x;
  int t = threadIdx.x;
  unsigned* cnt = bar;
  unsigned* gen = bar + 1;

  // Phase A: pow8 (blk<16) || reduce0 units 0..239 (blk 16..255)
  if (blk < 16)
    chain_body<0, 8>(arena, Rh, Rl, nullptr, nullptr, PowFp, R8h, R8l, blk);
  else
    chain_body<1, 8>(arena, Rh, Rl, nullptr, V0, V1, nullptr, nullptr, blk - 16);
  grid_bar(cnt, gen);

  // Phase B: reduce0 units 240..255 (blk<16) || pow64 (blk 16..31)
  if (blk < 16)
    chain_body<1, 8>(arena, Rh, Rl, nullptr, V0, V1, nullptr, nullptr, 240 + blk);
  else if (blk < 32)
    chain_body<0, 8>(arena, R8h, R8l, nullptr, nullptr, PowFp, R64h, R64l, blk - 16);
  grid_bar(cnt, gen);

  // Phase C: reduce1 (blk<32) || pow512 (blk 32..47)
  if (blk < 32)
    chain_body<1, 8>(arena, R8h, R8l, nullptr, V1, V2, nullptr, nullptr, blk);
  else if (blk < 48)
    chain_body<0, 8>(arena, R64h, R64l, nullptr, nullptr, R512fp, R512h, R512l, blk - 32);
  grid_bar(cnt, gen);

  // Phase D: reduce2 (blk<4)
  if (blk < 4)
    chain_body<1, 8>(arena, R64h, R64l, nullptr, V2, V3, nullptr, nullptr, blk);
  grid_bar(cnt, gen);

  // Phase E: top-level starts, 64 units @ stride 512, blk<16 x 4 units.
  // X3[k] = W[k-1] + R512*(W[k-2] + R512*W[k-3]) (3-term; exact k<=2;
  // k>=3 drops ||R^1536|| ~ 5e-7).
  {
    float* va = ((float*)arena) + (t >> 8) * 256;
    float* inner = ((float*)arena) + 1024 + (t >> 8) * 256;
    int ug = t >> 8, i = t & 255;
    int k = blk * 4 + ug;
    bool act = (blk < 16);
    if (act) {
      if (k >= 3)      va[i] = V3[(size_t)(k - 3) * 256 + i];
      else if (k == 2) va[i] = x0[i];
      else             va[i] = 0.f;
    }
    __syncthreads();
    if (act) {
      float innv = 0.f;
      if (k == 1) innv = x0[i];
      else if (k >= 2) {
        float acc = V3[(size_t)(k - 2) * 256 + i];
        const float* rr = R512fp + (size_t)i * 256;
        for (int j = 0; j < 256; j += 4) {
          float4 rv = *(const float4*)(rr + j);
          acc += rv.x * va[j] + rv.y * va[j + 1] + rv.z * va[j + 2] + rv.w * va[j + 3];
        }
        innv = acc;
      }
      inner[i] = innv;
    }
    __syncthreads();
    if (act) {
      if (k == 0) {
        X3[i] = x0[i];
      } else {
        float acc2 = V3[(size_t)(k - 1) * 256 + i];
        const float* rr2 = R512fp + (size_t)i * 256;
        for (int j = 0; j < 256; j += 4) {
          float4 rv = *(const float4*)(rr2 + j);
          acc2 += rv.x * inner[j] + rv.y * inner[j + 1] + rv.z * inner[j + 2] + rv.w * inner[j + 3];
        }
        X3[(size_t)k * 256 + i] = acc2;
      }
    }
  }
  grid_bar(cnt, gen);

  // Phase F: expand2 (blk<4)
  if (blk < 4)
    chain_body<2, 8>(arena, R64h, R64l, X3, V2, X2, nullptr, nullptr, blk);
  grid_bar(cnt, gen);

  // Phase G: expand1 (blk<32)
  if (blk < 32)
    chain_body<2, 8>(arena, R8h, R8l, X2, V1, X1, nullptr, nullptr, blk);
  grid_bar(cnt, gen);

  // Phase H: expand0 (all 256)
  chain_body<2, 8>(arena, Rh, Rl, X1, V0, xout, nullptr, nullptr, blk);
  grid_bar(cnt, gen);

  // Phase I: y = x @ C^T + u @ D^T (register-tiled 4x4, 256 active thr/block;
  // CsT transposed in LDS -> conflict-free; x straight from global/L3)
  {
    float (*CsT)[36] = reinterpret_cast<float(*)[36]>(arena);
    float (*DsT)[36] = reinterpret_cast<float(*)[36]>(arena + 36864);
    for (int k2 = t; k2 < 8192; k2 += 1024) CsT[k2 & 255][k2 >> 8] = Cm[k2];
    for (int k2 = t; k2 < 1024; k2 += 1024) DsT[k2 & 31][k2 >> 5] = Dm[k2];
    __syncthreads();
    if (t < 256) {
      int rt = t >> 3, ct = t & 7;
      int n0 = blk * 128 + rt * 4;
      int o0 = ct * 4;
      float acc[4][4] = {{0.f}};
#pragma unroll 4
      for (int i = 0; i < 256; i += 4) {
        float4 cv0 = *(const float4*)&CsT[i + 0][o0];
        float4 cv1 = *(const float4*)&CsT[i + 1][o0];
        float4 cv2 = *(const float4*)&CsT[i + 2][o0];
        float4 cv3 = *(const float4*)&CsT[i + 3][o0];
#pragma unroll
        for (int r = 0; r < 4; r++) {
          float4 xv = *(const float4*)(xout + (size_t)(n0 + r) * 256 + i);
          acc[r][0] += xv.x * cv0.x + xv.y * cv1.x + xv.z * cv2.x + xv.w * cv3.x;
          acc[r][1] += xv.x * cv0.y + xv.y * cv1.y + xv.z * cv2.y + xv.w * cv3.y;
          acc[r][2] += xv.x * cv0.z + xv.y * cv1.z + xv.z * cv2.z + xv.w * cv3.z;
          acc[r][3] += xv.x * cv0.w + xv.y * cv1.w + xv.z * cv2.w + xv.w * cv3.w;
        }
      }
#pragma unroll
      for (int i = 0; i < 32; i += 4) {
        float4 dv0 = *(const float4*)&DsT[i + 0][o0];
        float4 dv1 = *(const float4*)&DsT[i + 1][o0];
        float4 dv2 = *(const float4*)&DsT[i + 2][o0];
        float4 dv3 = *(const float4*)&DsT[i + 3][o0];
#pragma unroll
        for (int r = 0; r < 4; r++) {
          float4 uv = *(const float4*)(u + (size_t)(n0 + r) * 32 + i);
          acc[r][0] += uv.x * dv0.x + uv.y * dv1.x + uv.z * dv2.x + uv.w * dv3.x;
          acc[r][1] += uv.x * dv0.y + uv.y * dv1.y + uv.z * dv2.y + uv.w * dv3.y;
          acc[r][2] += uv.x * dv0.z + uv.y * dv1.z + uv.z * dv2.z + uv.w * dv3.z;
          acc[r][3] += uv.x * dv0.w + uv.y * dv1.w + uv.z * dv2.w + uv.w * dv3.w;
        }
      }
#pragma unroll
      for (int r = 0; r < 4; r++)
        *(float4*)(yout + (size_t)(n0 + r) * 32 + o0) =
            make_float4(acc[r][0], acc[r][1], acc[r][2], acc[r][3]);
    }
  }
}

// ---------------------------------------------------------------------------
// Drive GEMM with fused Hermite taps: C[M][256] = Wtap(u)[M][128] @ B[128][256].
// Tap row n, k = t*32+c: t0=u[n], t1=m_n, t2=u[n+1], t3=m_{n+1}; row 32767 = 0.
__global__ __launch_bounds__(256) void gemm_drive(const float* __restrict__ u,
                                                  const float* __restrict__ B,
                                                  float* __restrict__ C, int M) {
  int m0 = blockIdx.x * 128, n0 = blockIdx.y * 128;
  __shared__ float As[8][128];
  __shared__ float Bs[8][128];
  int tid = threadIdx.x;
  int am = tid >> 1, akc = (tid & 1) * 4;
  int bk = tid >> 5, bn = (tid & 31) * 4;
  int ty = tid >> 4, tx = tid & 15;
  int n = m0 + am;
  float acc[8][8] = {{0.f}};
  for (int kt = 0; kt < 128; kt += 8) {
    int tt = kt >> 5;
    int cb = (kt & 31) + akc;
    float4 av = make_float4(0.f, 0.f, 0.f, 0.f);
    if (n < TPTS - 1) {
      if (tt == 0) {
        av = *(const float4*)(u + (size_t)n * 32 + cb);
      } else if (tt == 1) {
        if (n == 0) {
          float4 a1 = *(const float4*)(u + 32 + cb);
          float4 a0 = *(const float4*)(u + cb);
          av = make_float4(a1.x - a0.x, a1.y - a0.y, a1.z - a0.z, a1.w - a0.w);
        } else {
          float4 ap = *(const float4*)(u + (size_t)(n + 1) * 32 + cb);
          float4 am4 = *(const float4*)(u + (size_t)(n - 1) * 32 + cb);
          av = make_float4(0.5f * (ap.x - am4.x), 0.5f * (ap.y - am4.y),
                           0.5f * (ap.z - am4.z), 0.5f * (ap.w - am4.w));
        }
      } else if (tt == 2) {
        av = *(const float4*)(u + (size_t)(n + 1) * 32 + cb);
      } else {
        if (n + 1 == TPTS - 1) {
          float4 a1 = *(const float4*)(u + (size_t)(TPTS - 1) * 32 + cb);
          float4 a0 = *(const float4*)(u + (size_t)(TPTS - 2) * 32 + cb);
          av = make_float4(a1.x - a0.x, a1.y - a0.y, a1.z - a0.z, a1.w - a0.w);
        } else {
          float4 ap = *(const float4*)(u + (size_t)(n + 2) * 32 + cb);
          float4 am4 = *(const float4*)(u + (size_t)n * 32 + cb);
          av = make_float4(0.5f * (ap.x - am4.x), 0.5f * (ap.y - am4.y),
                           0.5f * (ap.z - am4.z), 0.5f * (ap.w - am4.w));
        }
      }
    }
    float4 bv = *(const float4*)(B + (size_t)(kt + bk) * 256 + n0 + bn);
    __syncthreads();
    As[akc + 0][am] = av.x;
    As[akc + 1][am] = av.y;
    As[akc + 2][am] = av.z;
    As[akc + 3][am] = av.w;
    *(float4*)&Bs[bk][bn] = bv;
    __syncthreads();
#pragma unroll
    for (int kk = 0; kk < 8; kk++) {
      float4 a0 = *(const float4*)&As[kk][ty * 8];
      float4 a1 = *(const float4*)&As[kk][ty * 8 + 4];
      float4 b0 = *(const float4*)&Bs[kk][tx * 8];
      float4 b1 = *(const float4*)&Bs[kk][tx * 8 + 4];
      float ar[8] = {a0.x, a0.y, a0.z, a0.w, a1.x, a1.y, a1.z, a1.w};
      float br[8] = {b0.x, b0.y, b0.z, b0.w, b1.x, b1.y, b1.z, b1.w};
#pragma unroll
      for (int i = 0; i < 8; i++)
#pragma unroll
        for (int j = 0; j < 8; j++) acc[i][j] += ar[i] * br[j];
    }
  }
#pragma unroll
  for (int i = 0; i < 8; i++) {
    int row = m0 + ty * 8 + i;
    if (row < M) {
      *(float4*)&C[(size_t)row * 256 + n0 + tx * 8] = make_float4(acc[i][0], acc[i][1], acc[i][2], acc[i][3]);
      *(float4*)&C[(size_t)row * 256 + n0 + tx * 8 + 4] = make_float4(acc[i][4], acc[i][5], acc[i][6], acc[i][7]);
    }
  }
}

// AT = A^T (256x256); also zeroes the grid-barrier counters.
__global__ __launch_bounds__(256) void transpose_at(const float* __restrict__ A, float* __restrict__ AT,
                                                    unsigned* bar) {
  __shared__ float tile[64][65];
  int bx = blockIdx.x & 3, by = blockIdx.x >> 2;
  int r0 = by * 64, c0 = bx * 64;
  int t = threadIdx.x;
  if (blockIdx.x == 0 && t == 0) { bar[0] = 0u; bar[1] = 0u; }
  int lr = t >> 4, lc = (t & 15) * 4;
  for (int rr = lr; rr < 64; rr += 16) {
    float4 v = *(const float4*)(A + (size_t)(r0 + rr) * 256 + c0 + lc);
    tile[rr][lc + 0] = v.x; tile[rr][lc + 1] = v.y; tile[rr][lc + 2] = v.z; tile[rr][lc + 3] = v.w;
  }
  __syncthreads();
  for (int rr = lr; rr < 64; rr += 16) {
    float4 v = make_float4(tile[lc + 0][rr], tile[lc + 1][rr], tile[lc + 2][rr], tile[lc + 3][rr]);
    *(float4*)(AT + (size_t)(c0 + rr) * 256 + r0 + lc) = v;
  }
}

// Unit responses through one Dopri5 step: cols 0..255 -> R fp32 + bf16 hi/lo
// split; cols 256..383 -> Hermite-folded tap matrices transposed into FcatT.
// 1024 threads = 4 j-groups x 256 rows; 4-way split-K with LDS reduce.
__global__ __launch_bounds__(1024) void unit_resp(const float* __restrict__ AT,
                                                  const float* __restrict__ Bm,
                                                  float* __restrict__ Rout,
                                                  ushort_t* __restrict__ Rh,
                                                  ushort_t* __restrict__ Rl,
                                                  float* __restrict__ FcatT) {
  int blk = blockIdx.x;
  int tid = threadIdx.x;
  int jg = tid >> 8;   // j-group 0..3, also the owned column index cc
  int i = tid & 255;   // output row
  int cc = jg;
  int col = blk * 4 + cc;

  __shared__ float xs4[256][4];
  __shared__ float4 part[4][256];

  const float AA[6][5] = {
      {0.f, 0.f, 0.f, 0.f, 0.f},
      {0.2f, 0.f, 0.f, 0.f, 0.f},
      {3.f / 40.f, 9.f / 40.f, 0.f, 0.f, 0.f},
      {44.f / 45.f, -56.f / 15.f, 32.f / 9.f, 0.f, 0.f},
      {19372.f / 6561.f, -25360.f / 2187.f, 64448.f / 6561.f, -212.f / 729.f, 0.f},
      {9017.f / 3168.f, -355.f / 33.f, 46732.f / 5247.f, 49.f / 176.f, -5103.f / 18656.f}};
  const float BB[6] = {35.f / 384.f, 0.f, 500.f / 1113.f, 125.f / 192.f, -2187.f / 6784.f, 11.f / 84.f};
  const float sv[6] = {0.f, 0.2f, 0.3f, 0.8f, 8.f / 9.f, 1.f};
  float Hm[6][4];
#pragma unroll
  for (int s = 0; s < 6; s++) {
    float ss = sv[s], s2 = ss * ss, s3 = s2 * ss;
    Hm[s][0] = 2.f * s3 - 3.f * s2 + 1.f;
    Hm[s][1] = s3 - 2.f * s2 + ss;
    Hm[s][2] = -2.f * s3 + 3.f * s2;
    Hm[s][3] = s3 - s2;
  }

  // owned-column metadata
  int isF, tt;
  float brow, xc;
  if (col < 256) {
    isF = 0; tt = 0; brow = 0.f;
    xc = (i == col) ? 1.f : 0.f;
  } else {
    isF = 1; xc = 0.f;
    int f = col - 256;
    tt = f >> 5;
    brow = Bm[i * 32 + (f & 31)];
  }
  float bh[6];
#pragma unroll
  for (int s = 0; s < 6; s++) {
    float hv = (tt == 0) ? Hm[s][0] : ((tt == 1) ? Hm[s][1] : ((tt == 2) ? Hm[s][2] : Hm[s][3]));
    bh[s] = isF ? hv * brow : 0.f;
  }

  float kreg[6];
#pragma unroll
  for (int s = 0; s < 6; s++) kreg[s] = 0.f;

  int j0 = jg * 64;
#pragma unroll 1
  for (int s = 0; s < 6; s++) {
    float xsv = xc;
#pragma unroll
    for (int j = 0; j < 5; j++)
      if (j < s) xsv += AA[s][j] * kreg[j];
    xs4[i][cc] = xsv;
    __syncthreads();
    float acx = 0.f, acy = 0.f, acz = 0.f, acw = 0.f;
#pragma unroll 8
    for (int jj = 0; jj < 64; jj++) {
      int j = j0 + jj;
      float a = AT[(size_t)j * 256 + i];
      float4 xv = *(const float4*)xs4[j];
      acx += a * xv.x;
      acy += a * xv.y;
      acz += a * xv.z;
      acw += a * xv.w;
    }
    part[jg][i] = make_float4(acx, acy, acz, acw);
    __syncthreads();
    float k = bh[s];
#pragma unroll
    for (int g = 0; g < 4; g++) {
      const float* p = (const float*)&part[g][i];
      k += p[cc];
    }
    kreg[s] = k;
  }

  float o = xc;
#pragma unroll
  for (int s = 0; s < 6; s++) o += BB[s] * kreg[s];
  if (!isF) {
    Rout[(size_t)i * 256 + col] = o;
    ushort_t h = bf16_hi(o);
    Rh[(size_t)i * 256 + col] = h;
    Rl[(size_t)i * 256 + col] = bf16_hi(o - bf16_f(h));
  } else {
    FcatT[(size_t)(col - 256) * 256 + i] = o;
  }
}

extern "C" void kernel_launch(void* const* d_in, const int* in_sizes, int n_in,
                              void* d_out, int out_size, void* d_ws, size_t ws_size,
                              hipStream_t stream) {
  const float* u  = (const float*)d_in[1];
  const float* x0 = (const float*)d_in[2];
  const float* A  = (const float*)d_in[3];
  const float* Bm = (const float*)d_in[4];
  const float* Cm = (const float*)d_in[5];
  const float* Dm = (const float*)d_in[6];
  float* xout = (float*)d_out;                       // [32768][256]
  float* yout = xout + (size_t)TPTS * 256;           // [32768][32]

  char* wsb = (char*)d_ws;
  size_t off = 0;
  auto alloc = [&](size_t bytes) -> void* {
    void* p = (void*)(wsb + off);
    off = (off + bytes + 255) & ~(size_t)255;
    return p;
  };
  float*    Rfp    = (float*)alloc(65536 * 4);
  ushort_t* Rh     = (ushort_t*)alloc(65536 * 2);
  ushort_t* Rl     = (ushort_t*)alloc(65536 * 2);
  float*    PowFp  = (float*)alloc(65536 * 4);       // scratch fp out for R^8/R^64
  ushort_t* R8h    = (ushort_t*)alloc(65536 * 2);
  ushort_t* R8l    = (ushort_t*)alloc(65536 * 2);
  ushort_t* R64h   = (ushort_t*)alloc(65536 * 2);
  ushort_t* R64l   = (ushort_t*)alloc(65536 * 2);
  float*    R512fp = (float*)alloc(65536 * 4);
  ushort_t* R512h  = (ushort_t*)alloc(65536 * 2);
  ushort_t* R512l  = (ushort_t*)alloc(65536 * 2);
  float*    ATm    = (float*)alloc(65536 * 4);
  float*    FcatT  = (float*)alloc(128 * 256 * 4);
  float*    V0     = (float*)alloc((size_t)TPTS * 256 * 4);
  float*    V1     = (float*)alloc(4096 * 256 * 4);
  float*    V2     = (float*)alloc(512 * 256 * 4);
  float*    V3     = (float*)alloc(64 * 256 * 4);
  float*    X3     = (float*)alloc(64 * 256 * 4);
  float*    X2     = (float*)alloc(512 * 256 * 4);
  float*    X1     = (float*)alloc(4096 * 256 * 4);
  unsigned* bar    = (unsigned*)alloc(256);
  (void)ws_size; (void)in_sizes; (void)n_in; (void)out_size;

  // 1. A^T (+ barrier zero), unit responses -> R (fp32 + hi/lo) and FcatT
  transpose_at<<<dim3(16), dim3(256), 0, stream>>>(A, ATm, bar);
  unit_resp<<<dim3(96), dim3(1024), 0, stream>>>(ATm, Bm, Rfp, Rh, Rl, FcatT);

  // 2. drive v_n: fused Hermite taps + fp32 GEMM (K=128)
  gemm_drive<<<dim3(256, 2), dim3(256), 0, stream>>>(u, FcatT, V0, TPTS);

  // 3. everything else: one kernel (powers, reduces, top, expands, y)
  mega_scan<<<dim3(256), dim3(1024), 0, stream>>>(
      Rh, Rl, R8h, R8l, R64h, R64l, R512fp, R512h, R512l, PowFp,
      V0, V1, V2, V3, x0, X3, X2, X1, xout, u, Cm, Dm, yout, bar);
}

// Round 8
// 438.338 us; speedup vs baseline: 2.5340x; 2.5340x over previous
//
#include <hip/hip_runtime.h>

// Flow_49160195670664: Dopri5 fixed-step integration of dx/dt = A x + B u(t),
// T=32768, N=256, NI=NO=32, dt=1, Hermite-interpolated stage inputs.
// Linear system => x_{n+1} = R x_n + v_n with constant R.
// v4: 4-level blocked parallel scan 8 x 8 x 8 x 64.
// v5: y register-tiled 4x4. v6 (mega + grid barrier): FAILED — software grid
// barrier ~100us each on MI355X (r7: VALUBusy 1.7%, 1017us). v7: no barriers;
// fuse only INDEPENDENT phases as disjoint block ranges (pow8||gemm,
// pow64||reduce0, pow512||reduce1) and expand0+y (y block b reads exactly the
// xout rows block b wrote: threadfence+syncthreads suffices). 14 -> 10 launches.

#define TPTS 32768

typedef __attribute__((ext_vector_type(8))) short short8;
typedef __attribute__((ext_vector_type(4))) float float4v;
typedef unsigned short ushort_t;

__device__ __forceinline__ ushort_t bf16_hi(float f) {
  unsigned u = __builtin_bit_cast(unsigned, f);
  unsigned r = (u + 0x7FFFu + ((u >> 16) & 1u)) >> 16;
  return (ushort_t)r;
}
__device__ __forceinline__ float bf16_f(ushort_t h) {
  unsigned u = ((unsigned)h) << 16;
  return __builtin_bit_cast(float, u);
}

// ---------------------------------------------------------------------------
// MFMA chain body (device fn). 1024 thr = 16 waves; wave w owns output cols
// [16w,16w+16) as ONE N-tile of mfma_f32_16x16x32_bf16; 16 chains = M-dim.
// bf16 hi/lo split (x*R ~ xh*Rh + xl*Rh + xh*Rl, fp32 acc), 3 independent
// accumulators. V-drive register-prefetched one step ahead. blk is LOGICAL.
// MODE 0: power  (CLEN steps, x0 = I cols; Out = M^CLEN row-major fp32 + h/l)
// MODE 1: reduce (x0 = V row0 of chain, drive rows 1..CLEN-1; Out[chain]=final)
// MODE 2: expand (x0 = X0[chain], drive rows 0..CLEN-2; Out rows chain*CLEN+j)
// Arena: xh @0 (16KB), xl @16K (16KB), hist @32K (16KB MODE0/1, 80KB MODE2).
template <int MODE, int CLEN>
__device__ __forceinline__ void chain_body(char* arena, const ushort_t* Mh, const ushort_t* Ml,
                                           const float* X0, const float* V,
                                           float* Out, ushort_t* OutH, ushort_t* OutL, int blk) {
  constexpr int STEPS = (MODE == 0) ? CLEN : CLEN - 1;
  int t = threadIdx.x;
  int w = t >> 6, l = t & 63;   // w 0..15
  int q = l >> 4, c16 = l & 15;
  int n0 = w * 16;
  ushort_t (*xh)[32][16][8] = reinterpret_cast<ushort_t(*)[32][16][8]>(arena);
  ushort_t (*xl)[32][16][8] = reinterpret_cast<ushort_t(*)[32][16][8]>(arena + 16384);
  float (*hist)[16][256] = reinterpret_cast<float(*)[16][256]>(arena + 32768);
  // B-frags: B[k][n] = M[n][k]; lane holds B[kt*32+q*8+j][n0+c16], j=0..7
  short8 bh[8], bl[8];
#pragma unroll
  for (int kt = 0; kt < 8; kt++) {
    size_t offs = (size_t)(n0 + c16) * 256 + kt * 32 + q * 8;
    bh[kt] = *(const short8*)(Mh + offs);
    bl[kt] = *(const short8*)(Ml + offs);
  }
  // initial x (and row-0 store for MODE 2): 1024 float4, one per thread
  {
    int e = t;
    int c = e >> 6, qq = (e & 63) * 4;
    int cg = blk * 16 + c;
    float4 v4;
    if (MODE == 0) {
      v4 = make_float4(qq == cg ? 1.f : 0.f, qq + 1 == cg ? 1.f : 0.f,
                       qq + 2 == cg ? 1.f : 0.f, qq + 3 == cg ? 1.f : 0.f);
    } else if (MODE == 1) {
      v4 = *(const float4*)(V + (size_t)cg * CLEN * 256 + qq);
    } else {
      v4 = *(const float4*)(X0 + (size_t)cg * 256 + qq);
      *(float4*)(Out + ((size_t)cg * CLEN) * 256 + qq) = v4;
    }
    float vals[4] = {v4.x, v4.y, v4.z, v4.w};
#pragma unroll
    for (int i = 0; i < 4; i++) {
      int n = qq + i;
      ushort_t h = bf16_hi(vals[i]);
      xh[0][n >> 3][c][n & 7] = h;
      xl[0][n >> 3][c][n & 7] = bf16_hi(vals[i] - bf16_f(h));
    }
  }
  // per-lane drive prefetch for step 1 (element r: chain q*4+r, col n0+c16)
  float vnext[4];
  if (MODE != 0) {
#pragma unroll
    for (int r = 0; r < 4; r++) {
      int cg = blk * 16 + q * 4 + r;
      int drow = (MODE == 1) ? 1 : 0;
      vnext[r] = V[((size_t)cg * CLEN + drow) * 256 + n0 + c16];
    }
  }
  __syncthreads();
  for (int s = 1; s <= STEPS; s++) {
    int cur = (s - 1) & 1, nxt = s & 1;
    // MODE 2: flush rows s-4..s-1 (slots row%5) — mod-5 disjoint vs writes
    if (MODE == 2 && s >= 5 && ((s - 1) & 3) == 0) {
      int rbase = s - 4;
      for (int e = t; e < 4096; e += 1024) {
        int slot = e >> 10;
        int rem = e & 1023;
        int c = rem >> 6, qq = (rem & 63) * 4;
        int row = rbase + slot;
        int cg = blk * 16 + c;
        *(float4*)(Out + ((size_t)cg * CLEN + row) * 256 + qq) = *(const float4*)&hist[row % 5][c][qq];
      }
    }
    // drive: consume prefetched, issue next step's loads (hidden under MFMAs)
    float vc[4];
    if (MODE != 0) {
#pragma unroll
      for (int i2 = 0; i2 < 4; i2++) vc[i2] = vnext[i2];
      if (s < STEPS) {
        int drow = (MODE == 1) ? (s + 1) : s;
#pragma unroll
        for (int r = 0; r < 4; r++)
          vnext[r] = V[((size_t)(blk * 16 + q * 4 + r) * CLEN + drow) * 256 + n0 + c16];
      }
    }
    // pin frags: rw asm operand => value must live in VGPRs, reload illegal
#pragma unroll
    for (int kt = 0; kt < 8; kt++) {
      asm volatile("" : "+v"(bh[kt]));
      asm volatile("" : "+v"(bl[kt]));
    }
    float4v aH = {0.f, 0.f, 0.f, 0.f};
    float4v aL = {0.f, 0.f, 0.f, 0.f};
    float4v aC = {0.f, 0.f, 0.f, 0.f};
#pragma unroll
    for (int kt = 0; kt < 8; kt++) {
      short8 ah = *(const short8*)&xh[cur][kt * 4 + q][c16][0];
      short8 al = *(const short8*)&xl[cur][kt * 4 + q][c16][0];
      aH = __builtin_amdgcn_mfma_f32_16x16x32_bf16(ah, bh[kt], aH, 0, 0, 0);
      aL = __builtin_amdgcn_mfma_f32_16x16x32_bf16(al, bh[kt], aL, 0, 0, 0);
      aC = __builtin_amdgcn_mfma_f32_16x16x32_bf16(ah, bl[kt], aC, 0, 0, 0);
    }
    // epilogue: C/D layout chain=(q*4+r), col=c16 (m89-verified)
#pragma unroll
    for (int r = 0; r < 4; r++) {
      int c = q * 4 + r;
      int n = n0 + c16;
      float val = aH[r] + aL[r] + aC[r];
      if (MODE != 0) val += vc[r];
      int cg = blk * 16 + c;
      if (MODE == 2) hist[s % 5][c][n] = val;
      if (MODE == 1 && s == STEPS) Out[(size_t)cg * 256 + n] = val;
      if (MODE == 0 && s == STEPS) {
        ushort_t h2 = bf16_hi(val);
        Out[(size_t)n * 256 + cg] = val;
        OutH[(size_t)n * 256 + cg] = h2;
        OutL[(size_t)n * 256 + cg] = bf16_hi(val - bf16_f(h2));
      }
      ushort_t h = bf16_hi(val);
      xh[nxt][n >> 3][c][n & 7] = h;
      xl[nxt][n >> 3][c][n & 7] = bf16_hi(val - bf16_f(h));
    }
    __syncthreads();
  }
  if (MODE == 2) {   // final rows STEPS-2..STEPS
    for (int e = t; e < 3072; e += 1024) {
      int slot = e >> 10;
      int rem = e & 1023;
      int c = rem >> 6, qq = (rem & 63) * 4;
      int row = (STEPS - 2) + slot;
      int cg = blk * 16 + c;
      *(float4*)(Out + ((size_t)cg * CLEN + row) * 256 + qq) = *(const float4*)&hist[row % 5][c][qq];
    }
  }
}

// ---------------------------------------------------------------------------
// Hermite tap value: row n, k = t*32+c -> {u_n, m_n, u_{n+1}, m_{n+1}}[t][c].
// Row TPTS-1 = 0 (pad).  (logic identical to v6 gemm_drive, verified r5/r6)
__device__ __forceinline__ float tap_val(const float* __restrict__ u, int n, int k) {
  if (n >= TPTS - 1) return 0.f;
  int t = k >> 5, c = k & 31;
  if (t == 0) return u[(size_t)n * 32 + c];
  if (t == 2) return u[(size_t)(n + 1) * 32 + c];
  int kk = (t == 1) ? n : n + 1;
  if (kk == 0) return u[32 + c] - u[c];
  if (kk == TPTS - 1) return u[(size_t)(TPTS - 1) * 32 + c] - u[(size_t)(TPTS - 2) * 32 + c];
  return 0.5f * (u[(size_t)(kk + 1) * 32 + c] - u[(size_t)(kk - 1) * 32 + c]);
}

// Drive GEMM body, 1024 threads: V0[m0..m0+128)[n0..n0+128) = taps @ FcatT.
// 4x4 register tile per thread (32x32 threads). As padded [8][132] so the
// 8-lane-per-row staging write is conflict-free.
__device__ __forceinline__ void gemm_body(char* arena, const float* __restrict__ u,
                                          const float* __restrict__ B, float* __restrict__ C, int g) {
  float (*As)[132] = reinterpret_cast<float(*)[132]>(arena);          // 8x132
  float (*Bs)[128] = reinterpret_cast<float(*)[128]>(arena + 4224);   // 8x128
  int m0 = (g & 255) * 128, n0 = (g >> 8) * 128;
  int tid = threadIdx.x;
  int am = tid >> 3, ak = tid & 7;     // A-tile: 128 rows x 8 k
  int bk = tid >> 7, bn = tid & 127;   // B-tile: 8 k x 128 cols
  int ty = tid >> 5, tx = tid & 31;    // 32 x 32 -> 4x4 tile each
  float acc[4][4] = {{0.f}};
  for (int kt = 0; kt < 128; kt += 8) {
    float av = tap_val(u, m0 + am, kt + ak);
    float bv = B[(size_t)(kt + bk) * 256 + n0 + bn];
    __syncthreads();
    As[ak][am] = av;
    Bs[bk][bn] = bv;
    __syncthreads();
#pragma unroll
    for (int kk = 0; kk < 8; kk++) {
      float4 a = *(const float4*)&As[kk][ty * 4];
      float4 b = *(const float4*)&Bs[kk][tx * 4];
      float ar[4] = {a.x, a.y, a.z, a.w};
      float br[4] = {b.x, b.y, b.z, b.w};
#pragma unroll
      for (int i = 0; i < 4; i++)
#pragma unroll
        for (int j = 0; j < 4; j++) acc[i][j] += ar[i] * br[j];
    }
  }
#pragma unroll
  for (int i = 0; i < 4; i++) {
    int row = m0 + ty * 4 + i;
    *(float4*)&C[(size_t)row * 256 + n0 + tx * 4] =
        make_float4(acc[i][0], acc[i][1], acc[i][2], acc[i][3]);
  }
}

// ---------------------------------------------------------------------------
// Fused kernels (disjoint block ranges; no cross-block dependencies in-kernel)
__global__ __launch_bounds__(1024, 4) void pow8_gemm(const ushort_t* Rh, const ushort_t* Rl,
                                                     float* PowFp, ushort_t* R8h, ushort_t* R8l,
                                                     const float* u, const float* FcatT, float* V0) {
  __shared__ __attribute__((aligned(16))) char arena[49152];
  int blk = blockIdx.x;
  if (blk < 16)
    chain_body<0, 8>(arena, Rh, Rl, nullptr, nullptr, PowFp, R8h, R8l, blk);
  else
    gemm_body(arena, u, FcatT, V0, blk - 16);
}

__global__ __launch_bounds__(1024, 4) void pow64_reduce0(const ushort_t* R8h, const ushort_t* R8l,
                                                         float* PowFp, ushort_t* R64h, ushort_t* R64l,
                                                         const ushort_t* Rh, const ushort_t* Rl,
                                                         const float* V0, float* V1) {
  __shared__ __attribute__((aligned(16))) char arena[49152];
  int blk = blockIdx.x;
  if (blk < 16)
    chain_body<0, 8>(arena, R8h, R8l, nullptr, nullptr, PowFp, R64h, R64l, blk);
  else
    chain_body<1, 8>(arena, Rh, Rl, nullptr, V0, V1, nullptr, nullptr, blk - 16);
}

__global__ __launch_bounds__(1024, 4) void pow512_reduce1(const ushort_t* R64h, const ushort_t* R64l,
                                                          float* R512fp, ushort_t* R512h, ushort_t* R512l,
                                                          const ushort_t* R8h, const ushort_t* R8l,
                                                          const float* V1, float* V2) {
  __shared__ __attribute__((aligned(16))) char arena[49152];
  int blk = blockIdx.x;
  if (blk < 16)
    chain_body<0, 8>(arena, R64h, R64l, nullptr, nullptr, R512fp, R512h, R512l, blk);
  else
    chain_body<1, 8>(arena, R8h, R8l, nullptr, V1, V2, nullptr, nullptr, blk - 16);
}

__global__ __launch_bounds__(1024, 4) void reduce2_k(const ushort_t* R64h, const ushort_t* R64l,
                                                     const float* V2, float* V3) {
  __shared__ __attribute__((aligned(16))) char arena[49152];
  chain_body<1, 8>(arena, R64h, R64l, nullptr, V2, V3, nullptr, nullptr, blockIdx.x);
}

__global__ __launch_bounds__(1024, 4) void expand2_k(const ushort_t* R64h, const ushort_t* R64l,
                                                     const float* X3, const float* V2, float* X2) {
  __shared__ __attribute__((aligned(16))) char arena[114688];
  chain_body<2, 8>(arena, R64h, R64l, X3, V2, X2, nullptr, nullptr, blockIdx.x);
}

__global__ __launch_bounds__(1024, 4) void expand1_k(const ushort_t* R8h, const ushort_t* R8l,
                                                     const float* X2, const float* V1, float* X1) {
  __shared__ __attribute__((aligned(16))) char arena[114688];
  chain_body<2, 8>(arena, R8h, R8l, X2, V1, X1, nullptr, nullptr, blockIdx.x);
}

// expand0 + y fused: block b writes xout rows [128b, 128b+128) in chain_body,
// then computes y for exactly those rows (threadfence+barrier for visibility).
__global__ __launch_bounds__(1024, 4) void expand0_y(const ushort_t* Rh, const ushort_t* Rl,
                                                     const float* X1, const float* V0, float* xout,
                                                     const float* u, const float* Cm, const float* Dm,
                                                     float* yout) {
  __shared__ __attribute__((aligned(16))) char arena[114688];
  int blk = blockIdx.x;
  int t = threadIdx.x;
  chain_body<2, 8>(arena, Rh, Rl, X1, V0, xout, nullptr, nullptr, blk);
  __threadfence();
  __syncthreads();
  // y = x @ C^T + u @ D^T (register-tiled 4x4, threads 0..255; CsT transposed
  // in LDS -> conflict-free; x from global/L2, rows this block just wrote)
  float (*CsT)[36] = reinterpret_cast<float(*)[36]>(arena);
  float (*DsT)[36] = reinterpret_cast<float(*)[36]>(arena + 36864);
  for (int k2 = t; k2 < 8192; k2 += 1024) CsT[k2 & 255][k2 >> 8] = Cm[k2];
  for (int k2 = t; k2 < 1024; k2 += 1024) DsT[k2 & 31][k2 >> 5] = Dm[k2];
  __syncthreads();
  if (t < 256) {
    int rt = t >> 3, ct = t & 7;
    int n0 = blk * 128 + rt * 4;
    int o0 = ct * 4;
    float acc[4][4] = {{0.f}};
#pragma unroll 4
    for (int i = 0; i < 256; i += 4) {
      float4 cv0 = *(const float4*)&CsT[i + 0][o0];
      float4 cv1 = *(const float4*)&CsT[i + 1][o0];
      float4 cv2 = *(const float4*)&CsT[i + 2][o0];
      float4 cv3 = *(const float4*)&CsT[i + 3][o0];
#pragma unroll
      for (int r = 0; r < 4; r++) {
        float4 xv = *(const float4*)(xout + (size_t)(n0 + r) * 256 + i);
        acc[r][0] += xv.x * cv0.x + xv.y * cv1.x + xv.z * cv2.x + xv.w * cv3.x;
        acc[r][1] += xv.x * cv0.y + xv.y * cv1.y + xv.z * cv2.y + xv.w * cv3.y;
        acc[r][2] += xv.x * cv0.z + xv.y * cv1.z + xv.z * cv2.z + xv.w * cv3.z;
        acc[r][3] += xv.x * cv0.w + xv.y * cv1.w + xv.z * cv2.w + xv.w * cv3.w;
      }
    }
#pragma unroll
    for (int i = 0; i < 32; i += 4) {
      float4 dv0 = *(const float4*)&DsT[i + 0][o0];
      float4 dv1 = *(const float4*)&DsT[i + 1][o0];
      float4 dv2 = *(const float4*)&DsT[i + 2][o0];
      float4 dv3 = *(const float4*)&DsT[i + 3][o0];
#pragma unroll
      for (int r = 0; r < 4; r++) {
        float4 uv = *(const float4*)(u + (size_t)(n0 + r) * 32 + i);
        acc[r][0] += uv.x * dv0.x + uv.y * dv1.x + uv.z * dv2.x + uv.w * dv3.x;
        acc[r][1] += uv.x * dv0.y + uv.y * dv1.y + uv.z * dv2.y + uv.w * dv3.y;
        acc[r][2] += uv.x * dv0.z + uv.y * dv1.z + uv.z * dv2.z + uv.w * dv3.z;
        acc[r][3] += uv.x * dv0.w + uv.y * dv1.w + uv.z * dv2.w + uv.w * dv3.w;
      }
    }
#pragma unroll
    for (int r = 0; r < 4; r++)
      *(float4*)(yout + (size_t)(n0 + r) * 32 + o0) =
          make_float4(acc[r][0], acc[r][1], acc[r][2], acc[r][3]);
  }
}

// ---------------------------------------------------------------------------
// AT = A^T (256x256)
__global__ __launch_bounds__(256) void transpose_at(const float* __restrict__ A, float* __restrict__ AT) {
  __shared__ float tile[64][65];
  int bx = blockIdx.x & 3, by = blockIdx.x >> 2;
  int r0 = by * 64, c0 = bx * 64;
  int t = threadIdx.x;
  int lr = t >> 4, lc = (t & 15) * 4;
  for (int rr = lr; rr < 64; rr += 16) {
    float4 v = *(const float4*)(A + (size_t)(r0 + rr) * 256 + c0 + lc);
    tile[rr][lc + 0] = v.x; tile[rr][lc + 1] = v.y; tile[rr][lc + 2] = v.z; tile[rr][lc + 3] = v.w;
  }
  __syncthreads();
  for (int rr = lr; rr < 64; rr += 16) {
    float4 v = make_float4(tile[lc + 0][rr], tile[lc + 1][rr], tile[lc + 2][rr], tile[lc + 3][rr]);
    *(float4*)(AT + (size_t)(c0 + rr) * 256 + r0 + lc) = v;
  }
}

// Unit responses through one Dopri5 step: cols 0..255 -> R fp32 + bf16 hi/lo
// split; cols 256..383 -> Hermite-folded tap matrices transposed into FcatT.
// 1024 threads = 4 j-groups x 256 rows; 4-way split-K with LDS reduce.
__global__ __launch_bounds__(1024) void unit_resp(const float* __restrict__ AT,
                                                  const float* __restrict__ Bm,
                                                  float* __restrict__ Rout,
                                                  ushort_t* __restrict__ Rh,
                                                  ushort_t* __restrict__ Rl,
                                                  float* __restrict__ FcatT) {
  int blk = blockIdx.x;
  int tid = threadIdx.x;
  int jg = tid >> 8;   // j-group 0..3, also the owned column index cc
  int i = tid & 255;   // output row
  int cc = jg;
  int col = blk * 4 + cc;

  __shared__ float xs4[256][4];
  __shared__ float4 part[4][256];

  const float AA[6][5] = {
      {0.f, 0.f, 0.f, 0.f, 0.f},
      {0.2f, 0.f, 0.f, 0.f, 0.f},
      {3.f / 40.f, 9.f / 40.f, 0.f, 0.f, 0.f},
      {44.f / 45.f, -56.f / 15.f, 32.f / 9.f, 0.f, 0.f},
      {19372.f / 6561.f, -25360.f / 2187.f, 64448.f / 6561.f, -212.f / 729.f, 0.f},
      {9017.f / 3168.f, -355.f / 33.f, 46732.f / 5247.f, 49.f / 176.f, -5103.f / 18656.f}};
  const float BB[6] = {35.f / 384.f, 0.f, 500.f / 1113.f, 125.f / 192.f, -2187.f / 6784.f, 11.f / 84.f};
  const float sv[6] = {0.f, 0.2f, 0.3f, 0.8f, 8.f / 9.f, 1.f};
  float Hm[6][4];
#pragma unroll
  for (int s = 0; s < 6; s++) {
    float ss = sv[s], s2 = ss * ss, s3 = s2 * ss;
    Hm[s][0] = 2.f * s3 - 3.f * s2 + 1.f;
    Hm[s][1] = s3 - 2.f * s2 + ss;
    Hm[s][2] = -2.f * s3 + 3.f * s2;
    Hm[s][3] = s3 - s2;
  }

  // owned-column metadata
  int isF, tt;
  float brow, xc;
  if (col < 256) {
    isF = 0; tt = 0; brow = 0.f;
    xc = (i == col) ? 1.f : 0.f;
  } else {
    isF = 1; xc = 0.f;
    int f = col - 256;
    tt = f >> 5;
    brow = Bm[i * 32 + (f & 31)];
  }
  float bh[6];
#pragma unroll
  for (int s = 0; s < 6; s++) {
    float hv = (tt == 0) ? Hm[s][0] : ((tt == 1) ? Hm[s][1] : ((tt == 2) ? Hm[s][2] : Hm[s][3]));
    bh[s] = isF ? hv * brow : 0.f;
  }

  float kreg[6];
#pragma unroll
  for (int s = 0; s < 6; s++) kreg[s] = 0.f;

  int j0 = jg * 64;
#pragma unroll 1
  for (int s = 0; s < 6; s++) {
    float xsv = xc;
#pragma unroll
    for (int j = 0; j < 5; j++)
      if (j < s) xsv += AA[s][j] * kreg[j];
    xs4[i][cc] = xsv;
    __syncthreads();
    float acx = 0.f, acy = 0.f, acz = 0.f, acw = 0.f;
#pragma unroll 8
    for (int jj = 0; jj < 64; jj++) {
      int j = j0 + jj;
      float a = AT[(size_t)j * 256 + i];
      float4 xv = *(const float4*)xs4[j];
      acx += a * xv.x;
      acy += a * xv.y;
      acz += a * xv.z;
      acw += a * xv.w;
    }
    part[jg][i] = make_float4(acx, acy, acz, acw);
    __syncthreads();
    float k = bh[s];
#pragma unroll
    for (int g = 0; g < 4; g++) {
      const float* p = (const float*)&part[g][i];
      k += p[cc];
    }
    kreg[s] = k;
  }

  float o = xc;
#pragma unroll
  for (int s = 0; s < 6; s++) o += BB[s] * kreg[s];
  if (!isF) {
    Rout[(size_t)i * 256 + col] = o;
    ushort_t h = bf16_hi(o);
    Rh[(size_t)i * 256 + col] = h;
    Rl[(size_t)i * 256 + col] = bf16_hi(o - bf16_f(h));
  } else {
    FcatT[(size_t)(col - 256) * 256 + i] = o;
  }
}

// Top-level starts at stride 512: 64 blocks. X3[k] = x_{512k}.
// 3-term truncated recurrence (exact k<=2; k>=3 drops ||R^1536|| ~ 5e-7).
__global__ __launch_bounds__(256) void top_scan(const float* __restrict__ V3, const float* __restrict__ x0,
                                                const float* __restrict__ R512, float* __restrict__ X3) {
  int k = blockIdx.x, i = threadIdx.x;
  if (k == 0) { X3[i] = x0[i]; return; }
  __shared__ float va[256];
  __shared__ float inner[256];
  if (k == 1) {
    inner[i] = x0[i];
  } else {
    const float* vecA = (k == 2) ? x0 : (V3 + (size_t)(k - 3) * 256);
    va[i] = vecA[i];
    __syncthreads();
    float acc = V3[(size_t)(k - 2) * 256 + i];
    const float* rr = R512 + (size_t)i * 256;
    for (int j = 0; j < 256; j += 4) {
      float4 rv = *(const float4*)(rr + j);
      acc += rv.x * va[j] + rv.y * va[j + 1] + rv.z * va[j + 2] + rv.w * va[j + 3];
    }
    inner[i] = acc;
  }
  __syncthreads();
  float acc2 = V3[(size_t)(k - 1) * 256 + i];
  const float* rr2 = R512 + (size_t)i * 256;
  for (int j = 0; j < 256; j += 4) {
    float4 rv = *(const float4*)(rr2 + j);
    acc2 += rv.x * inner[j] + rv.y * inner[j + 1] + rv.z * inner[j + 2] + rv.w * inner[j + 3];
  }
  X3[(size_t)k * 256 + i] = acc2;
}

extern "C" void kernel_launch(void* const* d_in, const int* in_sizes, int n_in,
                              void* d_out, int out_size, void* d_ws, size_t ws_size,
                              hipStream_t stream) {
  const float* u  = (const float*)d_in[1];
  const float* x0 = (const float*)d_in[2];
  const float* A  = (const float*)d_in[3];
  const float* Bm = (const float*)d_in[4];
  const float* Cm = (const float*)d_in[5];
  const float* Dm = (const float*)d_in[6];
  float* xout = (float*)d_out;                       // [32768][256]
  float* yout = xout + (size_t)TPTS * 256;           // [32768][32]

  char* wsb = (char*)d_ws;
  size_t off = 0;
  auto alloc = [&](size_t bytes) -> void* {
    void* p = (void*)(wsb + off);
    off = (off + bytes + 255) & ~(size_t)255;
    return p;
  };
  float*    Rfp    = (float*)alloc(65536 * 4);
  ushort_t* Rh     = (ushort_t*)alloc(65536 * 2);
  ushort_t* Rl     = (ushort_t*)alloc(65536 * 2);
  float*    PowFp  = (float*)alloc(65536 * 4);       // scratch fp out for R^8/R^64
  ushort_t* R8h    = (ushort_t*)alloc(65536 * 2);
  ushort_t* R8l    = (ushort_t*)alloc(65536 * 2);
  ushort_t* R64h   = (ushort_t*)alloc(65536 * 2);
  ushort_t* R64l   = (ushort_t*)alloc(65536 * 2);
  float*    R512fp = (float*)alloc(65536 * 4);
  ushort_t* R512h  = (ushort_t*)alloc(65536 * 2);
  ushort_t* R512l  = (ushort_t*)alloc(65536 * 2);
  float*    ATm    = (float*)alloc(65536 * 4);
  float*    FcatT  = (float*)alloc(128 * 256 * 4);
  float*    V0     = (float*)alloc((size_t)TPTS * 256 * 4);
  float*    V1     = (float*)alloc(4096 * 256 * 4);
  float*    V2     = (float*)alloc(512 * 256 * 4);
  float*    V3     = (float*)alloc(64 * 256 * 4);
  float*    X3     = (float*)alloc(64 * 256 * 4);
  float*    X2     = (float*)alloc(512 * 256 * 4);
  float*    X1     = (float*)alloc(4096 * 256 * 4);
  (void)ws_size; (void)in_sizes; (void)n_in; (void)out_size;

  // 1. A^T; unit responses -> R (fp32 + hi/lo) and FcatT
  transpose_at<<<dim3(16), dim3(256), 0, stream>>>(A, ATm);
  unit_resp<<<dim3(96), dim3(1024), 0, stream>>>(ATm, Bm, Rfp, Rh, Rl, FcatT);

  // 2. pow8 (16 blk) || drive GEMM (512 blk) — independent given unit_resp
  pow8_gemm<<<dim3(528), dim3(1024), 0, stream>>>(Rh, Rl, PowFp, R8h, R8l, u, FcatT, V0);

  // 3. pow64 (16) || reduce0 (256)
  pow64_reduce0<<<dim3(272), dim3(1024), 0, stream>>>(R8h, R8l, PowFp, R64h, R64l, Rh, Rl, V0, V1);

  // 4. pow512 (16) || reduce1 (32)
  pow512_reduce1<<<dim3(48), dim3(1024), 0, stream>>>(R64h, R64l, R512fp, R512h, R512l, R8h, R8l, V1, V2);

  // 5. reduce2, top starts, expand down
  reduce2_k<<<dim3(4), dim3(1024), 0, stream>>>(R64h, R64l, V2, V3);
  top_scan<<<dim3(64), dim3(256), 0, stream>>>(V3, x0, R512fp, X3);
  expand2_k<<<dim3(4), dim3(1024), 0, stream>>>(R64h, R64l, X3, V2, X2);
  expand1_k<<<dim3(32), dim3(1024), 0, stream>>>(R8h, R8l, X2, V1, X1);

  // 6. expand0 + y fused (256 blk)
  expand0_y<<<dim3(256), dim3(1024), 0, stream>>>(Rh, Rl, X1, V0, xout, u, Cm, Dm, yout);
}

// Round 9
// 336.906 us; speedup vs baseline: 3.2969x; 1.3011x over previous
//
#include <hip/hip_runtime.h>

// Flow_49160195670664: Dopri5 fixed-step integration of dx/dt = A x + B u(t),
// T=32768, N=256, NI=NO=32, dt=1, Hermite-interpolated stage inputs.
// Linear system => x_{n+1} = R x_n + v_n with constant R.
// v4: 4-level blocked parallel scan 8 x 8 x 8 x 64.
// v5: y register-tiled 4x4. v6 (mega + grid barrier): FAILED (~100us/barrier).
// v7: barrier-free fusions (pow8||gemm, pow64||reduce0, pow512||reduce1,
// expand0+y). r8 counters: expand0_y was 177us, HBM-bound at 148MB/dispatch —
// the DEVICE-scope __threadfence() between the phases flushes L2 (+46MB
// writeback of dirty xout, +26MB re-fetch on the y reads). v8: block b's y
// phase reads only rows block b wrote -> __threadfence_block() (ordering, no
// L2 flush) is sufficient. One-line fix vs v7.

#define TPTS 32768

typedef __attribute__((ext_vector_type(8))) short short8;
typedef __attribute__((ext_vector_type(4))) float float4v;
typedef unsigned short ushort_t;

__device__ __forceinline__ ushort_t bf16_hi(float f) {
  unsigned u = __builtin_bit_cast(unsigned, f);
  unsigned r = (u + 0x7FFFu + ((u >> 16) & 1u)) >> 16;
  return (ushort_t)r;
}
__device__ __forceinline__ float bf16_f(ushort_t h) {
  unsigned u = ((unsigned)h) << 16;
  return __builtin_bit_cast(float, u);
}

// ---------------------------------------------------------------------------
// MFMA chain body (device fn). 1024 thr = 16 waves; wave w owns output cols
// [16w,16w+16) as ONE N-tile of mfma_f32_16x16x32_bf16; 16 chains = M-dim.
// bf16 hi/lo split (x*R ~ xh*Rh + xl*Rh + xh*Rl, fp32 acc), 3 independent
// accumulators. V-drive register-prefetched one step ahead. blk is LOGICAL.
// MODE 0: power  (CLEN steps, x0 = I cols; Out = M^CLEN row-major fp32 + h/l)
// MODE 1: reduce (x0 = V row0 of chain, drive rows 1..CLEN-1; Out[chain]=final)
// MODE 2: expand (x0 = X0[chain], drive rows 0..CLEN-2; Out rows chain*CLEN+j)
// Arena: xh @0 (16KB), xl @16K (16KB), hist @32K (16KB MODE0/1, 80KB MODE2).
template <int MODE, int CLEN>
__device__ __forceinline__ void chain_body(char* arena, const ushort_t* Mh, const ushort_t* Ml,
                                           const float* X0, const float* V,
                                           float* Out, ushort_t* OutH, ushort_t* OutL, int blk) {
  constexpr int STEPS = (MODE == 0) ? CLEN : CLEN - 1;
  int t = threadIdx.x;
  int w = t >> 6, l = t & 63;   // w 0..15
  int q = l >> 4, c16 = l & 15;
  int n0 = w * 16;
  ushort_t (*xh)[32][16][8] = reinterpret_cast<ushort_t(*)[32][16][8]>(arena);
  ushort_t (*xl)[32][16][8] = reinterpret_cast<ushort_t(*)[32][16][8]>(arena + 16384);
  float (*hist)[16][256] = reinterpret_cast<float(*)[16][256]>(arena + 32768);
  // B-frags: B[k][n] = M[n][k]; lane holds B[kt*32+q*8+j][n0+c16], j=0..7
  short8 bh[8], bl[8];
#pragma unroll
  for (int kt = 0; kt < 8; kt++) {
    size_t offs = (size_t)(n0 + c16) * 256 + kt * 32 + q * 8;
    bh[kt] = *(const short8*)(Mh + offs);
    bl[kt] = *(const short8*)(Ml + offs);
  }
  // initial x (and row-0 store for MODE 2): 1024 float4, one per thread
  {
    int e = t;
    int c = e >> 6, qq = (e & 63) * 4;
    int cg = blk * 16 + c;
    float4 v4;
    if (MODE == 0) {
      v4 = make_float4(qq == cg ? 1.f : 0.f, qq + 1 == cg ? 1.f : 0.f,
                       qq + 2 == cg ? 1.f : 0.f, qq + 3 == cg ? 1.f : 0.f);
    } else if (MODE == 1) {
      v4 = *(const float4*)(V + (size_t)cg * CLEN * 256 + qq);
    } else {
      v4 = *(const float4*)(X0 + (size_t)cg * 256 + qq);
      *(float4*)(Out + ((size_t)cg * CLEN) * 256 + qq) = v4;
    }
    float vals[4] = {v4.x, v4.y, v4.z, v4.w};
#pragma unroll
    for (int i = 0; i < 4; i++) {
      int n = qq + i;
      ushort_t h = bf16_hi(vals[i]);
      xh[0][n >> 3][c][n & 7] = h;
      xl[0][n >> 3][c][n & 7] = bf16_hi(vals[i] - bf16_f(h));
    }
  }
  // per-lane drive prefetch for step 1 (element r: chain q*4+r, col n0+c16)
  float vnext[4];
  if (MODE != 0) {
#pragma unroll
    for (int r = 0; r < 4; r++) {
      int cg = blk * 16 + q * 4 + r;
      int drow = (MODE == 1) ? 1 : 0;
      vnext[r] = V[((size_t)cg * CLEN + drow) * 256 + n0 + c16];
    }
  }
  __syncthreads();
  for (int s = 1; s <= STEPS; s++) {
    int cur = (s - 1) & 1, nxt = s & 1;
    // MODE 2: flush rows s-4..s-1 (slots row%5) — mod-5 disjoint vs writes
    if (MODE == 2 && s >= 5 && ((s - 1) & 3) == 0) {
      int rbase = s - 4;
      for (int e = t; e < 4096; e += 1024) {
        int slot = e >> 10;
        int rem = e & 1023;
        int c = rem >> 6, qq = (rem & 63) * 4;
        int row = rbase + slot;
        int cg = blk * 16 + c;
        *(float4*)(Out + ((size_t)cg * CLEN + row) * 256 + qq) = *(const float4*)&hist[row % 5][c][qq];
      }
    }
    // drive: consume prefetched, issue next step's loads (hidden under MFMAs)
    float vc[4];
    if (MODE != 0) {
#pragma unroll
      for (int i2 = 0; i2 < 4; i2++) vc[i2] = vnext[i2];
      if (s < STEPS) {
        int drow = (MODE == 1) ? (s + 1) : s;
#pragma unroll
        for (int r = 0; r < 4; r++)
          vnext[r] = V[((size_t)(blk * 16 + q * 4 + r) * CLEN + drow) * 256 + n0 + c16];
      }
    }
    // pin frags: rw asm operand => value must live in VGPRs, reload illegal
#pragma unroll
    for (int kt = 0; kt < 8; kt++) {
      asm volatile("" : "+v"(bh[kt]));
      asm volatile("" : "+v"(bl[kt]));
    }
    float4v aH = {0.f, 0.f, 0.f, 0.f};
    float4v aL = {0.f, 0.f, 0.f, 0.f};
    float4v aC = {0.f, 0.f, 0.f, 0.f};
#pragma unroll
    for (int kt = 0; kt < 8; kt++) {
      short8 ah = *(const short8*)&xh[cur][kt * 4 + q][c16][0];
      short8 al = *(const short8*)&xl[cur][kt * 4 + q][c16][0];
      aH = __builtin_amdgcn_mfma_f32_16x16x32_bf16(ah, bh[kt], aH, 0, 0, 0);
      aL = __builtin_amdgcn_mfma_f32_16x16x32_bf16(al, bh[kt], aL, 0, 0, 0);
      aC = __builtin_amdgcn_mfma_f32_16x16x32_bf16(ah, bl[kt], aC, 0, 0, 0);
    }
    // epilogue: C/D layout chain=(q*4+r), col=c16 (m89-verified)
#pragma unroll
    for (int r = 0; r < 4; r++) {
      int c = q * 4 + r;
      int n = n0 + c16;
      float val = aH[r] + aL[r] + aC[r];
      if (MODE != 0) val += vc[r];
      int cg = blk * 16 + c;
      if (MODE == 2) hist[s % 5][c][n] = val;
      if (MODE == 1 && s == STEPS) Out[(size_t)cg * 256 + n] = val;
      if (MODE == 0 && s == STEPS) {
        ushort_t h2 = bf16_hi(val);
        Out[(size_t)n * 256 + cg] = val;
        OutH[(size_t)n * 256 + cg] = h2;
        OutL[(size_t)n * 256 + cg] = bf16_hi(val - bf16_f(h2));
      }
      ushort_t h = bf16_hi(val);
      xh[nxt][n >> 3][c][n & 7] = h;
      xl[nxt][n >> 3][c][n & 7] = bf16_hi(val - bf16_f(h));
    }
    __syncthreads();
  }
  if (MODE == 2) {   // final rows STEPS-2..STEPS
    for (int e = t; e < 3072; e += 1024) {
      int slot = e >> 10;
      int rem = e & 1023;
      int c = rem >> 6, qq = (rem & 63) * 4;
      int row = (STEPS - 2) + slot;
      int cg = blk * 16 + c;
      *(float4*)(Out + ((size_t)cg * CLEN + row) * 256 + qq) = *(const float4*)&hist[row % 5][c][qq];
    }
  }
}

// ---------------------------------------------------------------------------
// Hermite tap value: row n, k = t*32+c -> {u_n, m_n, u_{n+1}, m_{n+1}}[t][c].
// Row TPTS-1 = 0 (pad).
__device__ __forceinline__ float tap_val(const float* __restrict__ u, int n, int k) {
  if (n >= TPTS - 1) return 0.f;
  int t = k >> 5, c = k & 31;
  if (t == 0) return u[(size_t)n * 32 + c];
  if (t == 2) return u[(size_t)(n + 1) * 32 + c];
  int kk = (t == 1) ? n : n + 1;
  if (kk == 0) return u[32 + c] - u[c];
  if (kk == TPTS - 1) return u[(size_t)(TPTS - 1) * 32 + c] - u[(size_t)(TPTS - 2) * 32 + c];
  return 0.5f * (u[(size_t)(kk + 1) * 32 + c] - u[(size_t)(kk - 1) * 32 + c]);
}

// Drive GEMM body, 1024 threads: V0[m0..m0+128)[n0..n0+128) = taps @ FcatT.
// 4x4 register tile per thread (32x32 threads). As padded [8][132].
__device__ __forceinline__ void gemm_body(char* arena, const float* __restrict__ u,
                                          const float* __restrict__ B, float* __restrict__ C, int g) {
  float (*As)[132] = reinterpret_cast<float(*)[132]>(arena);          // 8x132
  float (*Bs)[128] = reinterpret_cast<float(*)[128]>(arena + 4224);   // 8x128
  int m0 = (g & 255) * 128, n0 = (g >> 8) * 128;
  int tid = threadIdx.x;
  int am = tid >> 3, ak = tid & 7;     // A-tile: 128 rows x 8 k
  int bk = tid >> 7, bn = tid & 127;   // B-tile: 8 k x 128 cols
  int ty = tid >> 5, tx = tid & 31;    // 32 x 32 -> 4x4 tile each
  float acc[4][4] = {{0.f}};
  for (int kt = 0; kt < 128; kt += 8) {
    float av = tap_val(u, m0 + am, kt + ak);
    float bv = B[(size_t)(kt + bk) * 256 + n0 + bn];
    __syncthreads();
    As[ak][am] = av;
    Bs[bk][bn] = bv;
    __syncthreads();
#pragma unroll
    for (int kk = 0; kk < 8; kk++) {
      float4 a = *(const float4*)&As[kk][ty * 4];
      float4 b = *(const float4*)&Bs[kk][tx * 4];
      float ar[4] = {a.x, a.y, a.z, a.w};
      float br[4] = {b.x, b.y, b.z, b.w};
#pragma unroll
      for (int i = 0; i < 4; i++)
#pragma unroll
        for (int j = 0; j < 4; j++) acc[i][j] += ar[i] * br[j];
    }
  }
#pragma unroll
  for (int i = 0; i < 4; i++) {
    int row = m0 + ty * 4 + i;
    *(float4*)&C[(size_t)row * 256 + n0 + tx * 4] =
        make_float4(acc[i][0], acc[i][1], acc[i][2], acc[i][3]);
  }
}

// ---------------------------------------------------------------------------
// Fused kernels (disjoint block ranges; no cross-block dependencies in-kernel)
__global__ __launch_bounds__(1024, 4) void pow8_gemm(const ushort_t* Rh, const ushort_t* Rl,
                                                     float* PowFp, ushort_t* R8h, ushort_t* R8l,
                                                     const float* u, const float* FcatT, float* V0) {
  __shared__ __attribute__((aligned(16))) char arena[49152];
  int blk = blockIdx.x;
  if (blk < 16)
    chain_body<0, 8>(arena, Rh, Rl, nullptr, nullptr, PowFp, R8h, R8l, blk);
  else
    gemm_body(arena, u, FcatT, V0, blk - 16);
}

__global__ __launch_bounds__(1024, 4) void pow64_reduce0(const ushort_t* R8h, const ushort_t* R8l,
                                                         float* PowFp, ushort_t* R64h, ushort_t* R64l,
                                                         const ushort_t* Rh, const ushort_t* Rl,
                                                         const float* V0, float* V1) {
  __shared__ __attribute__((aligned(16))) char arena[49152];
  int blk = blockIdx.x;
  if (blk < 16)
    chain_body<0, 8>(arena, R8h, R8l, nullptr, nullptr, PowFp, R64h, R64l, blk);
  else
    chain_body<1, 8>(arena, Rh, Rl, nullptr, V0, V1, nullptr, nullptr, blk - 16);
}

__global__ __launch_bounds__(1024, 4) void pow512_reduce1(const ushort_t* R64h, const ushort_t* R64l,
                                                          float* R512fp, ushort_t* R512h, ushort_t* R512l,
                                                          const ushort_t* R8h, const ushort_t* R8l,
                                                          const float* V1, float* V2) {
  __shared__ __attribute__((aligned(16))) char arena[49152];
  int blk = blockIdx.x;
  if (blk < 16)
    chain_body<0, 8>(arena, R64h, R64l, nullptr, nullptr, R512fp, R512h, R512l, blk);
  else
    chain_body<1, 8>(arena, R8h, R8l, nullptr, V1, V2, nullptr, nullptr, blk - 16);
}

__global__ __launch_bounds__(1024, 4) void reduce2_k(const ushort_t* R64h, const ushort_t* R64l,
                                                     const float* V2, float* V3) {
  __shared__ __attribute__((aligned(16))) char arena[49152];
  chain_body<1, 8>(arena, R64h, R64l, nullptr, V2, V3, nullptr, nullptr, blockIdx.x);
}

__global__ __launch_bounds__(1024, 4) void expand2_k(const ushort_t* R64h, const ushort_t* R64l,
                                                     const float* X3, const float* V2, float* X2) {
  __shared__ __attribute__((aligned(16))) char arena[114688];
  chain_body<2, 8>(arena, R64h, R64l, X3, V2, X2, nullptr, nullptr, blockIdx.x);
}

__global__ __launch_bounds__(1024, 4) void expand1_k(const ushort_t* R8h, const ushort_t* R8l,
                                                     const float* X2, const float* V1, float* X1) {
  __shared__ __attribute__((aligned(16))) char arena[114688];
  chain_body<2, 8>(arena, R8h, R8l, X2, V1, X1, nullptr, nullptr, blockIdx.x);
}

// expand0 + y fused: block b writes xout rows [128b, 128b+128) in chain_body,
// then computes y for exactly those rows. Same-block producer/consumer =>
// __threadfence_block (ordering only, NO L2 flush — the device-scope fence in
// v7 flushed L2 and made this kernel HBM-bound at 177us/148MB, r8 counters).
__global__ __launch_bounds__(1024, 4) void expand0_y(const ushort_t* Rh, const ushort_t* Rl,
                                                     const float* X1, const float* V0, float* xout,
                                                     const float* u, const float* Cm, const float* Dm,
                                                     float* yout) {
  __shared__ __attribute__((aligned(16))) char arena[114688];
  int blk = blockIdx.x;
  int t = threadIdx.x;
  chain_body<2, 8>(arena, Rh, Rl, X1, V0, xout, nullptr, nullptr, blk);
  __threadfence_block();
  __syncthreads();
  // y = x @ C^T + u @ D^T (register-tiled 4x4, threads 0..255; CsT transposed
  // in LDS -> conflict-free; x from L1/L2, rows this block just wrote)
  float (*CsT)[36] = reinterpret_cast<float(*)[36]>(arena);
  float (*DsT)[36] = reinterpret_cast<float(*)[36]>(arena + 36864);
  for (int k2 = t; k2 < 8192; k2 += 1024) CsT[k2 & 255][k2 >> 8] = Cm[k2];
  for (int k2 = t; k2 < 1024; k2 += 1024) DsT[k2 & 31][k2 >> 5] = Dm[k2];
  __syncthreads();
  if (t < 256) {
    int rt = t >> 3, ct = t & 7;
    int n0 = blk * 128 + rt * 4;
    int o0 = ct * 4;
    float acc[4][4] = {{0.f}};
#pragma unroll 4
    for (int i = 0; i < 256; i += 4) {
      float4 cv0 = *(const float4*)&CsT[i + 0][o0];
      float4 cv1 = *(const float4*)&CsT[i + 1][o0];
      float4 cv2 = *(const float4*)&CsT[i + 2][o0];
      float4 cv3 = *(const float4*)&CsT[i + 3][o0];
#pragma unroll
      for (int r = 0; r < 4; r++) {
        float4 xv = *(const float4*)(xout + (size_t)(n0 + r) * 256 + i);
        acc[r][0] += xv.x * cv0.x + xv.y * cv1.x + xv.z * cv2.x + xv.w * cv3.x;
        acc[r][1] += xv.x * cv0.y + xv.y * cv1.y + xv.z * cv2.y + xv.w * cv3.y;
        acc[r][2] += xv.x * cv0.z + xv.y * cv1.z + xv.z * cv2.z + xv.w * cv3.z;
        acc[r][3] += xv.x * cv0.w + xv.y * cv1.w + xv.z * cv2.w + xv.w * cv3.w;
      }
    }
#pragma unroll
    for (int i = 0; i < 32; i += 4) {
      float4 dv0 = *(const float4*)&DsT[i + 0][o0];
      float4 dv1 = *(const float4*)&DsT[i + 1][o0];
      float4 dv2 = *(const float4*)&DsT[i + 2][o0];
      float4 dv3 = *(const float4*)&DsT[i + 3][o0];
#pragma unroll
      for (int r = 0; r < 4; r++) {
        float4 uv = *(const float4*)(u + (size_t)(n0 + r) * 32 + i);
        acc[r][0] += uv.x * dv0.x + uv.y * dv1.x + uv.z * dv2.x + uv.w * dv3.x;
        acc[r][1] += uv.x * dv0.y + uv.y * dv1.y + uv.z * dv2.y + uv.w * dv3.y;
        acc[r][2] += uv.x * dv0.z + uv.y * dv1.z + uv.z * dv2.z + uv.w * dv3.z;
        acc[r][3] += uv.x * dv0.w + uv.y * dv1.w + uv.z * dv2.w + uv.w * dv3.w;
      }
    }
#pragma unroll
    for (int r = 0; r < 4; r++)
      *(float4*)(yout + (size_t)(n0 + r) * 32 + o0) =
          make_float4(acc[r][0], acc[r][1], acc[r][2], acc[r][3]);
  }
}

// ---------------------------------------------------------------------------
// AT = A^T (256x256)
__global__ __launch_bounds__(256) void transpose_at(const float* __restrict__ A, float* __restrict__ AT) {
  __shared__ float tile[64][65];
  int bx = blockIdx.x & 3, by = blockIdx.x >> 2;
  int r0 = by * 64, c0 = bx * 64;
  int t = threadIdx.x;
  int lr = t >> 4, lc = (t & 15) * 4;
  for (int rr = lr; rr < 64; rr += 16) {
    float4 v = *(const float4*)(A + (size_t)(r0 + rr) * 256 + c0 + lc);
    tile[rr][lc + 0] = v.x; tile[rr][lc + 1] = v.y; tile[rr][lc + 2] = v.z; tile[rr][lc + 3] = v.w;
  }
  __syncthreads();
  for (int rr = lr; rr < 64; rr += 16) {
    float4 v = make_float4(tile[lc + 0][rr], tile[lc + 1][rr], tile[lc + 2][rr], tile[lc + 3][rr]);
    *(float4*)(AT + (size_t)(c0 + rr) * 256 + r0 + lc) = v;
  }
}

// Unit responses through one Dopri5 step: cols 0..255 -> R fp32 + bf16 hi/lo
// split; cols 256..383 -> Hermite-folded tap matrices transposed into FcatT.
// 1024 threads = 4 j-groups x 256 rows; 4-way split-K with LDS reduce.
__global__ __launch_bounds__(1024) void unit_resp(const float* __restrict__ AT,
                                                  const float* __restrict__ Bm,
                                                  float* __restrict__ Rout,
                                                  ushort_t* __restrict__ Rh,
                                                  ushort_t* __restrict__ Rl,
                                                  float* __restrict__ FcatT) {
  int blk = blockIdx.x;
  int tid = threadIdx.x;
  int jg = tid >> 8;   // j-group 0..3, also the owned column index cc
  int i = tid & 255;   // output row
  int cc = jg;
  int col = blk * 4 + cc;

  __shared__ float xs4[256][4];
  __shared__ float4 part[4][256];

  const float AA[6][5] = {
      {0.f, 0.f, 0.f, 0.f, 0.f},
      {0.2f, 0.f, 0.f, 0.f, 0.f},
      {3.f / 40.f, 9.f / 40.f, 0.f, 0.f, 0.f},
      {44.f / 45.f, -56.f / 15.f, 32.f / 9.f, 0.f, 0.f},
      {19372.f / 6561.f, -25360.f / 2187.f, 64448.f / 6561.f, -212.f / 729.f, 0.f},
      {9017.f / 3168.f, -355.f / 33.f, 46732.f / 5247.f, 49.f / 176.f, -5103.f / 18656.f}};
  const float BB[6] = {35.f / 384.f, 0.f, 500.f / 1113.f, 125.f / 192.f, -2187.f / 6784.f, 11.f / 84.f};
  const float sv[6] = {0.f, 0.2f, 0.3f, 0.8f, 8.f / 9.f, 1.f};
  float Hm[6][4];
#pragma unroll
  for (int s = 0; s < 6; s++) {
    float ss = sv[s], s2 = ss * ss, s3 = s2 * ss;
    Hm[s][0] = 2.f * s3 - 3.f * s2 + 1.f;
    Hm[s][1] = s3 - 2.f * s2 + ss;
    Hm[s][2] = -2.f * s3 + 3.f * s2;
    Hm[s][3] = s3 - s2;
  }

  // owned-column metadata
  int isF, tt;
  float brow, xc;
  if (col < 256) {
    isF = 0; tt = 0; brow = 0.f;
    xc = (i == col) ? 1.f : 0.f;
  } else {
    isF = 1; xc = 0.f;
    int f = col - 256;
    tt = f >> 5;
    brow = Bm[i * 32 + (f & 31)];
  }
  float bh[6];
#pragma unroll
  for (int s = 0; s < 6; s++) {
    float hv = (tt == 0) ? Hm[s][0] : ((tt == 1) ? Hm[s][1] : ((tt == 2) ? Hm[s][2] : Hm[s][3]));
    bh[s] = isF ? hv * brow : 0.f;
  }

  float kreg[6];
#pragma unroll
  for (int s = 0; s < 6; s++) kreg[s] = 0.f;

  int j0 = jg * 64;
#pragma unroll 1
  for (int s = 0; s < 6; s++) {
    float xsv = xc;
#pragma unroll
    for (int j = 0; j < 5; j++)
      if (j < s) xsv += AA[s][j] * kreg[j];
    xs4[i][cc] = xsv;
    __syncthreads();
    float acx = 0.f, acy = 0.f, acz = 0.f, acw = 0.f;
#pragma unroll 8
    for (int jj = 0; jj < 64; jj++) {
      int j = j0 + jj;
      float a = AT[(size_t)j * 256 + i];
      float4 xv = *(const float4*)xs4[j];
      acx += a * xv.x;
      acy += a * xv.y;
      acz += a * xv.z;
      acw += a * xv.w;
    }
    part[jg][i] = make_float4(acx, acy, acz, acw);
    __syncthreads();
    float k = bh[s];
#pragma unroll
    for (int g = 0; g < 4; g++) {
      const float* p = (const float*)&part[g][i];
      k += p[cc];
    }
    kreg[s] = k;
  }

  float o = xc;
#pragma unroll
  for (int s = 0; s < 6; s++) o += BB[s] * kreg[s];
  if (!isF) {
    Rout[(size_t)i * 256 + col] = o;
    ushort_t h = bf16_hi(o);
    Rh[(size_t)i * 256 + col] = h;
    Rl[(size_t)i * 256 + col] = bf16_hi(o - bf16_f(h));
  } else {
    FcatT[(size_t)(col - 256) * 256 + i] = o;
  }
}

// Top-level starts at stride 512: 64 blocks. X3[k] = x_{512k}.
// 3-term truncated recurrence (exact k<=2; k>=3 drops ||R^1536|| ~ 5e-7).
__global__ __launch_bounds__(256) void top_scan(const float* __restrict__ V3, const float* __restrict__ x0,
                                                const float* __restrict__ R512, float* __restrict__ X3) {
  int k = blockIdx.x, i = threadIdx.x;
  if (k == 0) { X3[i] = x0[i]; return; }
  __shared__ float va[256];
  __shared__ float inner[256];
  if (k == 1) {
    inner[i] = x0[i];
  } else {
    const float* vecA = (k == 2) ? x0 : (V3 + (size_t)(k - 3) * 256);
    va[i] = vecA[i];
    __syncthreads();
    float acc = V3[(size_t)(k - 2) * 256 + i];
    const float* rr = R512 + (size_t)i * 256;
    for (int j = 0; j < 256; j += 4) {
      float4 rv = *(const float4*)(rr + j);
      acc += rv.x * va[j] + rv.y * va[j + 1] + rv.z * va[j + 2] + rv.w * va[j + 3];
    }
    inner[i] = acc;
  }
  __syncthreads();
  float acc2 = V3[(size_t)(k - 1) * 256 + i];
  const float* rr2 = R512 + (size_t)i * 256;
  for (int j = 0; j < 256; j += 4) {
    float4 rv = *(const float4*)(rr2 + j);
    acc2 += rv.x * inner[j] + rv.y * inner[j + 1] + rv.z * inner[j + 2] + rv.w * inner[j + 3];
  }
  X3[(size_t)k * 256 + i] = acc2;
}

extern "C" void kernel_launch(void* const* d_in, const int* in_sizes, int n_in,
                              void* d_out, int out_size, void* d_ws, size_t ws_size,
                              hipStream_t stream) {
  const float* u  = (const float*)d_in[1];
  const float* x0 = (const float*)d_in[2];
  const float* A  = (const float*)d_in[3];
  const float* Bm = (const float*)d_in[4];
  const float* Cm = (const float*)d_in[5];
  const float* Dm = (const float*)d_in[6];
  float* xout = (float*)d_out;                       // [32768][256]
  float* yout = xout + (size_t)TPTS * 256;           // [32768][32]

  char* wsb = (char*)d_ws;
  size_t off = 0;
  auto alloc = [&](size_t bytes) -> void* {
    void* p = (void*)(wsb + off);
    off = (off + bytes + 255) & ~(size_t)255;
    return p;
  };
  float*    Rfp    = (float*)alloc(65536 * 4);
  ushort_t* Rh     = (ushort_t*)alloc(65536 * 2);
  ushort_t* Rl     = (ushort_t*)alloc(65536 * 2);
  float*    PowFp  = (float*)alloc(65536 * 4);       // scratch fp out for R^8/R^64
  ushort_t* R8h    = (ushort_t*)alloc(65536 * 2);
  ushort_t* R8l    = (ushort_t*)alloc(65536 * 2);
  ushort_t* R64h   = (ushort_t*)alloc(65536 * 2);
  ushort_t* R64l   = (ushort_t*)alloc(65536 * 2);
  float*    R512fp = (float*)alloc(65536 * 4);
  ushort_t* R512h  = (ushort_t*)alloc(65536 * 2);
  ushort_t* R512l  = (ushort_t*)alloc(65536 * 2);
  float*    ATm    = (float*)alloc(65536 * 4);
  float*    FcatT  = (float*)alloc(128 * 256 * 4);
  float*    V0     = (float*)alloc((size_t)TPTS * 256 * 4);
  float*    V1     = (float*)alloc(4096 * 256 * 4);
  float*    V2     = (float*)alloc(512 * 256 * 4);
  float*    V3     = (float*)alloc(64 * 256 * 4);
  float*    X3     = (float*)alloc(64 * 256 * 4);
  float*    X2     = (float*)alloc(512 * 256 * 4);
  float*    X1     = (float*)alloc(4096 * 256 * 4);
  (void)ws_size; (void)in_sizes; (void)n_in; (void)out_size;

  // 1. A^T; unit responses -> R (fp32 + hi/lo) and FcatT
  transpose_at<<<dim3(16), dim3(256), 0, stream>>>(A, ATm);
  unit_resp<<<dim3(96), dim3(1024), 0, stream>>>(ATm, Bm, Rfp, Rh, Rl, FcatT);

  // 2. pow8 (16 blk) || drive GEMM (512 blk) — independent given unit_resp
  pow8_gemm<<<dim3(528), dim3(1024), 0, stream>>>(Rh, Rl, PowFp, R8h, R8l, u, FcatT, V0);

  // 3. pow64 (16) || reduce0 (256)
  pow64_reduce0<<<dim3(272), dim3(1024), 0, stream>>>(R8h, R8l, PowFp, R64h, R64l, Rh, Rl, V0, V1);

  // 4. pow512 (16) || reduce1 (32)
  pow512_reduce1<<<dim3(48), dim3(1024), 0, stream>>>(R64h, R64l, R512fp, R512h, R512l, R8h, R8l, V1, V2);

  // 5. reduce2, top starts, expand down
  reduce2_k<<<dim3(4), dim3(1024), 0, stream>>>(R64h, R64l, V2, V3);
  top_scan<<<dim3(64), dim3(256), 0, stream>>>(V3, x0, R512fp, X3);
  expand2_k<<<dim3(4), dim3(1024), 0, stream>>>(R64h, R64l, X3, V2, X2);
  expand1_k<<<dim3(32), dim3(1024), 0, stream>>>(R8h, R8l, X2, V1, X1);

  // 6. expand0 + y fused (256 blk)
  expand0_y<<<dim3(256), dim3(1024), 0, stream>>>(Rh, Rl, X1, V0, xout, u, Cm, Dm, yout);
}

// Round 11
// 314.495 us; speedup vs baseline: 3.5319x; 1.0713x over previous
//
#include <hip/hip_runtime.h>

// Flow_49160195670664: Dopri5 fixed-step integration of dx/dt = A x + B u(t),
// T=32768, N=256, NI=NO=32, dt=1, Hermite-interpolated stage inputs.
// Linear system => x_{n+1} = R x_n + v_n with constant R.
// v4: 4-level blocked parallel scan 8 x 8 x 8 x 64.
// v5: y register-tiled 4x4. v6 (grid barrier): FAILED (~100us/barrier).
// v7/v8: barrier-free fusions. r9 counters: expand0_y fused kernel carries
// +64MB structural excess traffic (62/82MB vs 40/36 expected) IDENTICAL across
// fence scopes -> fence theory dead; prime suspect is VGPR spill (1024-thr
// block caps unified VGPR+AGPR at 128/thread; chain phase alone fits exactly,
// r3). v9: unfuse expand0 and y (both individually verified clean); keep the
// pow8||gemm, pow64||reduce0, pow512||reduce1 fusions.

#define TPTS 32768

typedef __attribute__((ext_vector_type(8))) short short8;
typedef __attribute__((ext_vector_type(4))) float float4v;
typedef unsigned short ushort_t;

__device__ __forceinline__ ushort_t bf16_hi(float f) {
  unsigned u = __builtin_bit_cast(unsigned, f);
  unsigned r = (u + 0x7FFFu + ((u >> 16) & 1u)) >> 16;
  return (ushort_t)r;
}
__device__ __forceinline__ float bf16_f(ushort_t h) {
  unsigned u = ((unsigned)h) << 16;
  return __builtin_bit_cast(float, u);
}

// ---------------------------------------------------------------------------
// MFMA chain body (device fn). 1024 thr = 16 waves; wave w owns output cols
// [16w,16w+16) as ONE N-tile of mfma_f32_16x16x32_bf16; 16 chains = M-dim.
// bf16 hi/lo split (x*R ~ xh*Rh + xl*Rh + xh*Rl, fp32 acc), 3 independent
// accumulators. V-drive register-prefetched one step ahead. blk is LOGICAL.
// MODE 0: power  (CLEN steps, x0 = I cols; Out = M^CLEN row-major fp32 + h/l)
// MODE 1: reduce (x0 = V row0 of chain, drive rows 1..CLEN-1; Out[chain]=final)
// MODE 2: expand (x0 = X0[chain], drive rows 0..CLEN-2; Out rows chain*CLEN+j)
// Arena: xh @0 (16KB), xl @16K (16KB), hist @32K (16KB MODE0/1, 80KB MODE2).
template <int MODE, int CLEN>
__device__ __forceinline__ void chain_body(char* arena, const ushort_t* Mh, const ushort_t* Ml,
                                           const float* X0, const float* V,
                                           float* Out, ushort_t* OutH, ushort_t* OutL, int blk) {
  constexpr int STEPS = (MODE == 0) ? CLEN : CLEN - 1;
  int t = threadIdx.x;
  int w = t >> 6, l = t & 63;   // w 0..15
  int q = l >> 4, c16 = l & 15;
  int n0 = w * 16;
  ushort_t (*xh)[32][16][8] = reinterpret_cast<ushort_t(*)[32][16][8]>(arena);
  ushort_t (*xl)[32][16][8] = reinterpret_cast<ushort_t(*)[32][16][8]>(arena + 16384);
  float (*hist)[16][256] = reinterpret_cast<float(*)[16][256]>(arena + 32768);
  // B-frags: B[k][n] = M[n][k]; lane holds B[kt*32+q*8+j][n0+c16], j=0..7
  short8 bh[8], bl[8];
#pragma unroll
  for (int kt = 0; kt < 8; kt++) {
    size_t offs = (size_t)(n0 + c16) * 256 + kt * 32 + q * 8;
    bh[kt] = *(const short8*)(Mh + offs);
    bl[kt] = *(const short8*)(Ml + offs);
  }
  // initial x (and row-0 store for MODE 2): 1024 float4, one per thread
  {
    int e = t;
    int c = e >> 6, qq = (e & 63) * 4;
    int cg = blk * 16 + c;
    float4 v4;
    if (MODE == 0) {
      v4 = make_float4(qq == cg ? 1.f : 0.f, qq + 1 == cg ? 1.f : 0.f,
                       qq + 2 == cg ? 1.f : 0.f, qq + 3 == cg ? 1.f : 0.f);
    } else if (MODE == 1) {
      v4 = *(const float4*)(V + (size_t)cg * CLEN * 256 + qq);
    } else {
      v4 = *(const float4*)(X0 + (size_t)cg * 256 + qq);
      *(float4*)(Out + ((size_t)cg * CLEN) * 256 + qq) = v4;
    }
    float vals[4] = {v4.x, v4.y, v4.z, v4.w};
#pragma unroll
    for (int i = 0; i < 4; i++) {
      int n = qq + i;
      ushort_t h = bf16_hi(vals[i]);
      xh[0][n >> 3][c][n & 7] = h;
      xl[0][n >> 3][c][n & 7] = bf16_hi(vals[i] - bf16_f(h));
    }
  }
  // per-lane drive prefetch for step 1 (element r: chain q*4+r, col n0+c16)
  float vnext[4];
  if (MODE != 0) {
#pragma unroll
    for (int r = 0; r < 4; r++) {
      int cg = blk * 16 + q * 4 + r;
      int drow = (MODE == 1) ? 1 : 0;
      vnext[r] = V[((size_t)cg * CLEN + drow) * 256 + n0 + c16];
    }
  }
  __syncthreads();
  for (int s = 1; s <= STEPS; s++) {
    int cur = (s - 1) & 1, nxt = s & 1;
    // MODE 2: flush rows s-4..s-1 (slots row%5) — mod-5 disjoint vs writes
    if (MODE == 2 && s >= 5 && ((s - 1) & 3) == 0) {
      int rbase = s - 4;
      for (int e = t; e < 4096; e += 1024) {
        int slot = e >> 10;
        int rem = e & 1023;
        int c = rem >> 6, qq = (rem & 63) * 4;
        int row = rbase + slot;
        int cg = blk * 16 + c;
        *(float4*)(Out + ((size_t)cg * CLEN + row) * 256 + qq) = *(const float4*)&hist[row % 5][c][qq];
      }
    }
    // drive: consume prefetched, issue next step's loads (hidden under MFMAs)
    float vc[4];
    if (MODE != 0) {
#pragma unroll
      for (int i2 = 0; i2 < 4; i2++) vc[i2] = vnext[i2];
      if (s < STEPS) {
        int drow = (MODE == 1) ? (s + 1) : s;
#pragma unroll
        for (int r = 0; r < 4; r++)
          vnext[r] = V[((size_t)(blk * 16 + q * 4 + r) * CLEN + drow) * 256 + n0 + c16];
      }
    }
    // pin frags: rw asm operand => value must live in VGPRs, reload illegal
#pragma unroll
    for (int kt = 0; kt < 8; kt++) {
      asm volatile("" : "+v"(bh[kt]));
      asm volatile("" : "+v"(bl[kt]));
    }
    float4v aH = {0.f, 0.f, 0.f, 0.f};
    float4v aL = {0.f, 0.f, 0.f, 0.f};
    float4v aC = {0.f, 0.f, 0.f, 0.f};
#pragma unroll
    for (int kt = 0; kt < 8; kt++) {
      short8 ah = *(const short8*)&xh[cur][kt * 4 + q][c16][0];
      short8 al = *(const short8*)&xl[cur][kt * 4 + q][c16][0];
      aH = __builtin_amdgcn_mfma_f32_16x16x32_bf16(ah, bh[kt], aH, 0, 0, 0);
      aL = __builtin_amdgcn_mfma_f32_16x16x32_bf16(al, bh[kt], aL, 0, 0, 0);
      aC = __builtin_amdgcn_mfma_f32_16x16x32_bf16(ah, bl[kt], aC, 0, 0, 0);
    }
    // epilogue: C/D layout chain=(q*4+r), col=c16 (m89-verified)
#pragma unroll
    for (int r = 0; r < 4; r++) {
      int c = q * 4 + r;
      int n = n0 + c16;
      float val = aH[r] + aL[r] + aC[r];
      if (MODE != 0) val += vc[r];
      int cg = blk * 16 + c;
      if (MODE == 2) hist[s % 5][c][n] = val;
      if (MODE == 1 && s == STEPS) Out[(size_t)cg * 256 + n] = val;
      if (MODE == 0 && s == STEPS) {
        ushort_t h2 = bf16_hi(val);
        Out[(size_t)n * 256 + cg] = val;
        OutH[(size_t)n * 256 + cg] = h2;
        OutL[(size_t)n * 256 + cg] = bf16_hi(val - bf16_f(h2));
      }
      ushort_t h = bf16_hi(val);
      xh[nxt][n >> 3][c][n & 7] = h;
      xl[nxt][n >> 3][c][n & 7] = bf16_hi(val - bf16_f(h));
    }
    __syncthreads();
  }
  if (MODE == 2) {   // final rows STEPS-2..STEPS
    for (int e = t; e < 3072; e += 1024) {
      int slot = e >> 10;
      int rem = e & 1023;
      int c = rem >> 6, qq = (rem & 63) * 4;
      int row = (STEPS - 2) + slot;
      int cg = blk * 16 + c;
      *(float4*)(Out + ((size_t)cg * CLEN + row) * 256 + qq) = *(const float4*)&hist[row % 5][c][qq];
    }
  }
}

// ---------------------------------------------------------------------------
// Hermite tap value: row n, k = t*32+c -> {u_n, m_n, u_{n+1}, m_{n+1}}[t][c].
// Row TPTS-1 = 0 (pad).
__device__ __forceinline__ float tap_val(const float* __restrict__ u, int n, int k) {
  if (n >= TPTS - 1) return 0.f;
  int t = k >> 5, c = k & 31;
  if (t == 0) return u[(size_t)n * 32 + c];
  if (t == 2) return u[(size_t)(n + 1) * 32 + c];
  int kk = (t == 1) ? n : n + 1;
  if (kk == 0) return u[32 + c] - u[c];
  if (kk == TPTS - 1) return u[(size_t)(TPTS - 1) * 32 + c] - u[(size_t)(TPTS - 2) * 32 + c];
  return 0.5f * (u[(size_t)(kk + 1) * 32 + c] - u[(size_t)(kk - 1) * 32 + c]);
}

// Drive GEMM body, 1024 threads: V0[m0..m0+128)[n0..n0+128) = taps @ FcatT.
// 4x4 register tile per thread (32x32 threads). As padded [8][132].
__device__ __forceinline__ void gemm_body(char* arena, const float* __restrict__ u,
                                          const float* __restrict__ B, float* __restrict__ C, int g) {
  float (*As)[132] = reinterpret_cast<float(*)[132]>(arena);          // 8x132
  float (*Bs)[128] = reinterpret_cast<float(*)[128]>(arena + 4224);   // 8x128
  int m0 = (g & 255) * 128, n0 = (g >> 8) * 128;
  int tid = threadIdx.x;
  int am = tid >> 3, ak = tid & 7;     // A-tile: 128 rows x 8 k
  int bk = tid >> 7, bn = tid & 127;   // B-tile: 8 k x 128 cols
  int ty = tid >> 5, tx = tid & 31;    // 32 x 32 -> 4x4 tile each
  float acc[4][4] = {{0.f}};
  for (int kt = 0; kt < 128; kt += 8) {
    float av = tap_val(u, m0 + am, kt + ak);
    float bv = B[(size_t)(kt + bk) * 256 + n0 + bn];
    __syncthreads();
    As[ak][am] = av;
    Bs[bk][bn] = bv;
    __syncthreads();
#pragma unroll
    for (int kk = 0; kk < 8; kk++) {
      float4 a = *(const float4*)&As[kk][ty * 4];
      float4 b = *(const float4*)&Bs[kk][tx * 4];
      float ar[4] = {a.x, a.y, a.z, a.w};
      float br[4] = {b.x, b.y, b.z, b.w};
#pragma unroll
      for (int i = 0; i < 4; i++)
#pragma unroll
        for (int j = 0; j < 4; j++) acc[i][j] += ar[i] * br[j];
    }
  }
#pragma unroll
  for (int i = 0; i < 4; i++) {
    int row = m0 + ty * 4 + i;
    *(float4*)&C[(size_t)row * 256 + n0 + tx * 4] =
        make_float4(acc[i][0], acc[i][1], acc[i][2], acc[i][3]);
  }
}

// ---------------------------------------------------------------------------
// Fused kernels (disjoint block ranges; no cross-block dependencies in-kernel)
__global__ __launch_bounds__(1024, 4) void pow8_gemm(const ushort_t* Rh, const ushort_t* Rl,
                                                     float* PowFp, ushort_t* R8h, ushort_t* R8l,
                                                     const float* u, const float* FcatT, float* V0) {
  __shared__ __attribute__((aligned(16))) char arena[49152];
  int blk = blockIdx.x;
  if (blk < 16)
    chain_body<0, 8>(arena, Rh, Rl, nullptr, nullptr, PowFp, R8h, R8l, blk);
  else
    gemm_body(arena, u, FcatT, V0, blk - 16);
}

__global__ __launch_bounds__(1024, 4) void pow64_reduce0(const ushort_t* R8h, const ushort_t* R8l,
                                                         float* PowFp, ushort_t* R64h, ushort_t* R64l,
                                                         const ushort_t* Rh, const ushort_t* Rl,
                                                         const float* V0, float* V1) {
  __shared__ __attribute__((aligned(16))) char arena[49152];
  int blk = blockIdx.x;
  if (blk < 16)
    chain_body<0, 8>(arena, R8h, R8l, nullptr, nullptr, PowFp, R64h, R64l, blk);
  else
    chain_body<1, 8>(arena, Rh, Rl, nullptr, V0, V1, nullptr, nullptr, blk - 16);
}

__global__ __launch_bounds__(1024, 4) void pow512_reduce1(const ushort_t* R64h, const ushort_t* R64l,
                                                          float* R512fp, ushort_t* R512h, ushort_t* R512l,
                                                          const ushort_t* R8h, const ushort_t* R8l,
                                                          const float* V1, float* V2) {
  __shared__ __attribute__((aligned(16))) char arena[49152];
  int blk = blockIdx.x;
  if (blk < 16)
    chain_body<0, 8>(arena, R64h, R64l, nullptr, nullptr, R512fp, R512h, R512l, blk);
  else
    chain_body<1, 8>(arena, R8h, R8l, nullptr, V1, V2, nullptr, nullptr, blk - 16);
}

__global__ __launch_bounds__(1024, 4) void reduce2_k(const ushort_t* R64h, const ushort_t* R64l,
                                                     const float* V2, float* V3) {
  __shared__ __attribute__((aligned(16))) char arena[49152];
  chain_body<1, 8>(arena, R64h, R64l, nullptr, V2, V3, nullptr, nullptr, blockIdx.x);
}

__global__ __launch_bounds__(1024, 4) void expand2_k(const ushort_t* R64h, const ushort_t* R64l,
                                                     const float* X3, const float* V2, float* X2) {
  __shared__ __attribute__((aligned(16))) char arena[114688];
  chain_body<2, 8>(arena, R64h, R64l, X3, V2, X2, nullptr, nullptr, blockIdx.x);
}

__global__ __launch_bounds__(1024, 4) void expand1_k(const ushort_t* R8h, const ushort_t* R8l,
                                                     const float* X2, const float* V1, float* X1) {
  __shared__ __attribute__((aligned(16))) char arena[114688];
  chain_body<2, 8>(arena, R8h, R8l, X2, V1, X1, nullptr, nullptr, blockIdx.x);
}

__global__ __launch_bounds__(1024, 4) void expand0_k(const ushort_t* Rh, const ushort_t* Rl,
                                                     const float* X1, const float* V0, float* xout) {
  __shared__ __attribute__((aligned(16))) char arena[114688];
  chain_body<2, 8>(arena, Rh, Rl, X1, V0, xout, nullptr, nullptr, blockIdx.x);
}

// ---------------------------------------------------------------------------
// y = x @ C^T + u @ D^T. Register-tiled 4x4 (v5-verified). 256 blocks x 256
// thr; thread (rt,ct) computes rows n0+rt*4+0..3 x cols ct*4+0..3. C/D stored
// TRANSPOSED in LDS (conflict-free); x read straight from global (L2/L3).
__global__ __launch_bounds__(256) void y_kernel(const float* __restrict__ x, const float* __restrict__ u,
                                                const float* __restrict__ Cm, const float* __restrict__ Dm,
                                                float* __restrict__ y) {
  __shared__ float CsT[256][36];
  __shared__ float DsT[32][36];
  int tid = threadIdx.x;
  for (int k = tid; k < 8192; k += 256) CsT[k & 255][k >> 8] = Cm[k];
  for (int k = tid; k < 1024; k += 256) DsT[k & 31][k >> 5] = Dm[k];
  __syncthreads();
  int rt = tid >> 3, ct = tid & 7;
  int n0 = blockIdx.x * 128 + rt * 4;
  int o0 = ct * 4;
  float acc[4][4] = {{0.f}};
#pragma unroll 4
  for (int i = 0; i < 256; i += 4) {
    float4 cv0 = *(const float4*)&CsT[i + 0][o0];
    float4 cv1 = *(const float4*)&CsT[i + 1][o0];
    float4 cv2 = *(const float4*)&CsT[i + 2][o0];
    float4 cv3 = *(const float4*)&CsT[i + 3][o0];
#pragma unroll
    for (int r = 0; r < 4; r++) {
      float4 xv = *(const float4*)(x + (size_t)(n0 + r) * 256 + i);
      acc[r][0] += xv.x * cv0.x + xv.y * cv1.x + xv.z * cv2.x + xv.w * cv3.x;
      acc[r][1] += xv.x * cv0.y + xv.y * cv1.y + xv.z * cv2.y + xv.w * cv3.y;
      acc[r][2] += xv.x * cv0.z + xv.y * cv1.z + xv.z * cv2.z + xv.w * cv3.z;
      acc[r][3] += xv.x * cv0.w + xv.y * cv1.w + xv.z * cv2.w + xv.w * cv3.w;
    }
  }
#pragma unroll
  for (int i = 0; i < 32; i += 4) {
    float4 dv0 = *(const float4*)&DsT[i + 0][o0];
    float4 dv1 = *(const float4*)&DsT[i + 1][o0];
    float4 dv2 = *(const float4*)&DsT[i + 2][o0];
    float4 dv3 = *(const float4*)&DsT[i + 3][o0];
#pragma unroll
    for (int r = 0; r < 4; r++) {
      float4 uv = *(const float4*)(u + (size_t)(n0 + r) * 32 + i);
      acc[r][0] += uv.x * dv0.x + uv.y * dv1.x + uv.z * dv2.x + uv.w * dv3.x;
      acc[r][1] += uv.x * dv0.y + uv.y * dv1.y + uv.z * dv2.y + uv.w * dv3.y;
      acc[r][2] += uv.x * dv0.z + uv.y * dv1.z + uv.z * dv2.z + uv.w * dv3.z;
      acc[r][3] += uv.x * dv0.w + uv.y * dv1.w + uv.z * dv2.w + uv.w * dv3.w;
    }
  }
#pragma unroll
  for (int r = 0; r < 4; r++)
    *(float4*)(y + (size_t)(n0 + r) * 32 + o0) =
        make_float4(acc[r][0], acc[r][1], acc[r][2], acc[r][3]);
}

// ---------------------------------------------------------------------------
// AT = A^T (256x256)
__global__ __launch_bounds__(256) void transpose_at(const float* __restrict__ A, float* __restrict__ AT) {
  __shared__ float tile[64][65];
  int bx = blockIdx.x & 3, by = blockIdx.x >> 2;
  int r0 = by * 64, c0 = bx * 64;
  int t = threadIdx.x;
  int lr = t >> 4, lc = (t & 15) * 4;
  for (int rr = lr; rr < 64; rr += 16) {
    float4 v = *(const float4*)(A + (size_t)(r0 + rr) * 256 + c0 + lc);
    tile[rr][lc + 0] = v.x; tile[rr][lc + 1] = v.y; tile[rr][lc + 2] = v.z; tile[rr][lc + 3] = v.w;
  }
  __syncthreads();
  for (int rr = lr; rr < 64; rr += 16) {
    float4 v = make_float4(tile[lc + 0][rr], tile[lc + 1][rr], tile[lc + 2][rr], tile[lc + 3][rr]);
    *(float4*)(AT + (size_t)(c0 + rr) * 256 + r0 + lc) = v;
  }
}

// Unit responses through one Dopri5 step: cols 0..255 -> R fp32 + bf16 hi/lo
// split; cols 256..383 -> Hermite-folded tap matrices transposed into FcatT.
// 1024 threads = 4 j-groups x 256 rows; 4-way split-K with LDS reduce.
__global__ __launch_bounds__(1024) void unit_resp(const float* __restrict__ AT,
                                                  const float* __restrict__ Bm,
                                                  float* __restrict__ Rout,
                                                  ushort_t* __restrict__ Rh,
                                                  ushort_t* __restrict__ Rl,
                                                  float* __restrict__ FcatT) {
  int blk = blockIdx.x;
  int tid = threadIdx.x;
  int jg = tid >> 8;   // j-group 0..3, also the owned column index cc
  int i = tid & 255;   // output row
  int cc = jg;
  int col = blk * 4 + cc;

  __shared__ float xs4[256][4];
  __shared__ float4 part[4][256];

  const float AA[6][5] = {
      {0.f, 0.f, 0.f, 0.f, 0.f},
      {0.2f, 0.f, 0.f, 0.f, 0.f},
      {3.f / 40.f, 9.f / 40.f, 0.f, 0.f, 0.f},
      {44.f / 45.f, -56.f / 15.f, 32.f / 9.f, 0.f, 0.f},
      {19372.f / 6561.f, -25360.f / 2187.f, 64448.f / 6561.f, -212.f / 729.f, 0.f},
      {9017.f / 3168.f, -355.f / 33.f, 46732.f / 5247.f, 49.f / 176.f, -5103.f / 18656.f}};
  const float BB[6] = {35.f / 384.f, 0.f, 500.f / 1113.f, 125.f / 192.f, -2187.f / 6784.f, 11.f / 84.f};
  const float sv[6] = {0.f, 0.2f, 0.3f, 0.8f, 8.f / 9.f, 1.f};
  float Hm[6][4];
#pragma unroll
  for (int s = 0; s < 6; s++) {
    float ss = sv[s], s2 = ss * ss, s3 = s2 * ss;
    Hm[s][0] = 2.f * s3 - 3.f * s2 + 1.f;
    Hm[s][1] = s3 - 2.f * s2 + ss;
    Hm[s][2] = -2.f * s3 + 3.f * s2;
    Hm[s][3] = s3 - s2;
  }

  // owned-column metadata
  int isF, tt;
  float brow, xc;
  if (col < 256) {
    isF = 0; tt = 0; brow = 0.f;
    xc = (i == col) ? 1.f : 0.f;
  } else {
    isF = 1; xc = 0.f;
    int f = col - 256;
    tt = f >> 5;
    brow = Bm[i * 32 + (f & 31)];
  }
  float bh[6];
#pragma unroll
  for (int s = 0; s < 6; s++) {
    float hv = (tt == 0) ? Hm[s][0] : ((tt == 1) ? Hm[s][1] : ((tt == 2) ? Hm[s][2] : Hm[s][3]));
    bh[s] = isF ? hv * brow : 0.f;
  }

  float kreg[6];
#pragma unroll
  for (int s = 0; s < 6; s++) kreg[s] = 0.f;

  int j0 = jg * 64;
#pragma unroll 1
  for (int s = 0; s < 6; s++) {
    float xsv = xc;
#pragma unroll
    for (int j = 0; j < 5; j++)
      if (j < s) xsv += AA[s][j] * kreg[j];
    xs4[i][cc] = xsv;
    __syncthreads();
    float acx = 0.f, acy = 0.f, acz = 0.f, acw = 0.f;
#pragma unroll 8
    for (int jj = 0; jj < 64; jj++) {
      int j = j0 + jj;
      float a = AT[(size_t)j * 256 + i];
      float4 xv = *(const float4*)xs4[j];
      acx += a * xv.x;
      acy += a * xv.y;
      acz += a * xv.z;
      acw += a * xv.w;
    }
    part[jg][i] = make_float4(acx, acy, acz, acw);
    __syncthreads();
    float k = bh[s];
#pragma unroll
    for (int g = 0; g < 4; g++) {
      const float* p = (const float*)&part[g][i];
      k += p[cc];
    }
    kreg[s] = k;
  }

  float o = xc;
#pragma unroll
  for (int s = 0; s < 6; s++) o += BB[s] * kreg[s];
  if (!isF) {
    Rout[(size_t)i * 256 + col] = o;
    ushort_t h = bf16_hi(o);
    Rh[(size_t)i * 256 + col] = h;
    Rl[(size_t)i * 256 + col] = bf16_hi(o - bf16_f(h));
  } else {
    FcatT[(size_t)(col - 256) * 256 + i] = o;
  }
}

// Top-level starts at stride 512: 64 blocks. X3[k] = x_{512k}.
// 3-term truncated recurrence (exact k<=2; k>=3 drops ||R^1536|| ~ 5e-7).
__global__ __launch_bounds__(256) void top_scan(const float* __restrict__ V3, const float* __restrict__ x0,
                                                const float* __restrict__ R512, float* __restrict__ X3) {
  int k = blockIdx.x, i = threadIdx.x;
  if (k == 0) { X3[i] = x0[i]; return; }
  __shared__ float va[256];
  __shared__ float inner[256];
  if (k == 1) {
    inner[i] = x0[i];
  } else {
    const float* vecA = (k == 2) ? x0 : (V3 + (size_t)(k - 3) * 256);
    va[i] = vecA[i];
    __syncthreads();
    float acc = V3[(size_t)(k - 2) * 256 + i];
    const float* rr = R512 + (size_t)i * 256;
    for (int j = 0; j < 256; j += 4) {
      float4 rv = *(const float4*)(rr + j);
      acc += rv.x * va[j] + rv.y * va[j + 1] + rv.z * va[j + 2] + rv.w * va[j + 3];
    }
    inner[i] = acc;
  }
  __syncthreads();
  float acc2 = V3[(size_t)(k - 1) * 256 + i];
  const float* rr2 = R512 + (size_t)i * 256;
  for (int j = 0; j < 256; j += 4) {
    float4 rv = *(const float4*)(rr2 + j);
    acc2 += rv.x * inner[j] + rv.y * inner[j + 1] + rv.z * inner[j + 2] + rv.w * inner[j + 3];
  }
  X3[(size_t)k * 256 + i] = acc2;
}

extern "C" void kernel_launch(void* const* d_in, const int* in_sizes, int n_in,
                              void* d_out, int out_size, void* d_ws, size_t ws_size,
                              hipStream_t stream) {
  const float* u  = (const float*)d_in[1];
  const float* x0 = (const float*)d_in[2];
  const float* A  = (const float*)d_in[3];
  const float* Bm = (const float*)d_in[4];
  const float* Cm = (const float*)d_in[5];
  const float* Dm = (const float*)d_in[6];
  float* xout = (float*)d_out;                       // [32768][256]
  float* yout = xout + (size_t)TPTS * 256;           // [32768][32]

  char* wsb = (char*)d_ws;
  size_t off = 0;
  auto alloc = [&](size_t bytes) -> void* {
    void* p = (void*)(wsb + off);
    off = (off + bytes + 255) & ~(size_t)255;
    return p;
  };
  float*    Rfp    = (float*)alloc(65536 * 4);
  ushort_t* Rh     = (ushort_t*)alloc(65536 * 2);
  ushort_t* Rl     = (ushort_t*)alloc(65536 * 2);
  float*    PowFp  = (float*)alloc(65536 * 4);       // scratch fp out for R^8/R^64
  ushort_t* R8h    = (ushort_t*)alloc(65536 * 2);
  ushort_t* R8l    = (ushort_t*)alloc(65536 * 2);
  ushort_t* R64h   = (ushort_t*)alloc(65536 * 2);
  ushort_t* R64l   = (ushort_t*)alloc(65536 * 2);
  float*    R512fp = (float*)alloc(65536 * 4);
  ushort_t* R512h  = (ushort_t*)alloc(65536 * 2);
  ushort_t* R512l  = (ushort_t*)alloc(65536 * 2);
  float*    ATm    = (float*)alloc(65536 * 4);
  float*    FcatT  = (float*)alloc(128 * 256 * 4);
  float*    V0     = (float*)alloc((size_t)TPTS * 256 * 4);
  float*    V1     = (float*)alloc(4096 * 256 * 4);
  float*    V2     = (float*)alloc(512 * 256 * 4);
  float*    V3     = (float*)alloc(64 * 256 * 4);
  float*    X3     = (float*)alloc(64 * 256 * 4);
  float*    X2     = (float*)alloc(512 * 256 * 4);
  float*    X1     = (float*)alloc(4096 * 256 * 4);
  (void)ws_size; (void)in_sizes; (void)n_in; (void)out_size;

  // 1. A^T; unit responses -> R (fp32 + hi/lo) and FcatT
  transpose_at<<<dim3(16), dim3(256), 0, stream>>>(A, ATm);
  unit_resp<<<dim3(96), dim3(1024), 0, stream>>>(ATm, Bm, Rfp, Rh, Rl, FcatT);

  // 2. pow8 (16 blk) || drive GEMM (512 blk) — independent given unit_resp
  pow8_gemm<<<dim3(528), dim3(1024), 0, stream>>>(Rh, Rl, PowFp, R8h, R8l, u, FcatT, V0);

  // 3. pow64 (16) || reduce0 (256)
  pow64_reduce0<<<dim3(272), dim3(1024), 0, stream>>>(R8h, R8l, PowFp, R64h, R64l, Rh, Rl, V0, V1);

  // 4. pow512 (16) || reduce1 (32)
  pow512_reduce1<<<dim3(48), dim3(1024), 0, stream>>>(R64h, R64l, R512fp, R512h, R512l, R8h, R8l, V1, V2);

  // 5. reduce2, top starts, expand down
  reduce2_k<<<dim3(4), dim3(1024), 0, stream>>>(R64h, R64l, V2, V3);
  top_scan<<<dim3(64), dim3(256), 0, stream>>>(V3, x0, R512fp, X3);
  expand2_k<<<dim3(4), dim3(1024), 0, stream>>>(R64h, R64l, X3, V2, X2);
  expand1_k<<<dim3(32), dim3(1024), 0, stream>>>(R8h, R8l, X2, V1, X1);

  // 6. expand0, then y (separate launches — fused version carried +64MB
  //    structural excess traffic, r8/r9 counters)
  expand0_k<<<dim3(256), dim3(1024), 0, stream>>>(Rh, Rl, X1, V0, xout);
  y_kernel<<<dim3(256), dim3(256), 0, stream>>>(xout, u, Cm, Dm, yout);
}

// Round 12
// 288.190 us; speedup vs baseline: 3.8543x; 1.0913x over previous
//
#include <hip/hip_runtime.h>

// Flow_49160195670664: Dopri5 fixed-step integration of dx/dt = A x + B u(t),
// T=32768, N=256, NI=NO=32, dt=1, Hermite-interpolated stage inputs.
// Linear system => x_{n+1} = R x_n + v_n with constant R.
// v4: 4-level blocked parallel scan 8 x 8 x 8 x 64.
// v5: y register-tiled 4x4. v6 (grid barrier): FAILED (~100us/barrier).
// v7/v8: barrier-free fusions; v9: expand0/y unfused (fused carried +64MB).
// v10: drive GEMM on MFMA. r11 counters: fp32 gemm_body was LDS-read-bound
// (16 FMA / 32B LDS -> 2.15GB LDS traffic ~31us floor; measured 61us,
// VALUBusy 28%). Now: taps -> bf16 hi/lo staged in LDS (chain_body's exact
// [k>>3][row][k&7] layout), F matrix pre-split to Fh/Fl[n][k] in unit_resp,
// 12 MFMA per wave per 16-row group (3-product hi/lo split). LDS traffic /8,
// kernel becomes V0-write-bound (~33MB) || pow8 chain.

#define TPTS 32768

typedef __attribute__((ext_vector_type(8))) short short8;
typedef __attribute__((ext_vector_type(4))) float float4v;
typedef unsigned short ushort_t;

__device__ __forceinline__ ushort_t bf16_hi(float f) {
  unsigned u = __builtin_bit_cast(unsigned, f);
  unsigned r = (u + 0x7FFFu + ((u >> 16) & 1u)) >> 16;
  return (ushort_t)r;
}
__device__ __forceinline__ float bf16_f(ushort_t h) {
  unsigned u = ((unsigned)h) << 16;
  return __builtin_bit_cast(float, u);
}

// ---------------------------------------------------------------------------
// MFMA chain body (device fn). 1024 thr = 16 waves; wave w owns output cols
// [16w,16w+16) as ONE N-tile of mfma_f32_16x16x32_bf16; 16 chains = M-dim.
// bf16 hi/lo split (x*R ~ xh*Rh + xl*Rh + xh*Rl, fp32 acc), 3 independent
// accumulators. V-drive register-prefetched one step ahead. blk is LOGICAL.
// MODE 0: power  (CLEN steps, x0 = I cols; Out = M^CLEN row-major fp32 + h/l)
// MODE 1: reduce (x0 = V row0 of chain, drive rows 1..CLEN-1; Out[chain]=final)
// MODE 2: expand (x0 = X0[chain], drive rows 0..CLEN-2; Out rows chain*CLEN+j)
// Arena: xh @0 (16KB), xl @16K (16KB), hist @32K (16KB MODE0/1, 80KB MODE2).
template <int MODE, int CLEN>
__device__ __forceinline__ void chain_body(char* arena, const ushort_t* Mh, const ushort_t* Ml,
                                           const float* X0, const float* V,
                                           float* Out, ushort_t* OutH, ushort_t* OutL, int blk) {
  constexpr int STEPS = (MODE == 0) ? CLEN : CLEN - 1;
  int t = threadIdx.x;
  int w = t >> 6, l = t & 63;   // w 0..15
  int q = l >> 4, c16 = l & 15;
  int n0 = w * 16;
  ushort_t (*xh)[32][16][8] = reinterpret_cast<ushort_t(*)[32][16][8]>(arena);
  ushort_t (*xl)[32][16][8] = reinterpret_cast<ushort_t(*)[32][16][8]>(arena + 16384);
  float (*hist)[16][256] = reinterpret_cast<float(*)[16][256]>(arena + 32768);
  // B-frags: B[k][n] = M[n][k]; lane holds B[kt*32+q*8+j][n0+c16], j=0..7
  short8 bh[8], bl[8];
#pragma unroll
  for (int kt = 0; kt < 8; kt++) {
    size_t offs = (size_t)(n0 + c16) * 256 + kt * 32 + q * 8;
    bh[kt] = *(const short8*)(Mh + offs);
    bl[kt] = *(const short8*)(Ml + offs);
  }
  // initial x (and row-0 store for MODE 2): 1024 float4, one per thread
  {
    int e = t;
    int c = e >> 6, qq = (e & 63) * 4;
    int cg = blk * 16 + c;
    float4 v4;
    if (MODE == 0) {
      v4 = make_float4(qq == cg ? 1.f : 0.f, qq + 1 == cg ? 1.f : 0.f,
                       qq + 2 == cg ? 1.f : 0.f, qq + 3 == cg ? 1.f : 0.f);
    } else if (MODE == 1) {
      v4 = *(const float4*)(V + (size_t)cg * CLEN * 256 + qq);
    } else {
      v4 = *(const float4*)(X0 + (size_t)cg * 256 + qq);
      *(float4*)(Out + ((size_t)cg * CLEN) * 256 + qq) = v4;
    }
    float vals[4] = {v4.x, v4.y, v4.z, v4.w};
#pragma unroll
    for (int i = 0; i < 4; i++) {
      int n = qq + i;
      ushort_t h = bf16_hi(vals[i]);
      xh[0][n >> 3][c][n & 7] = h;
      xl[0][n >> 3][c][n & 7] = bf16_hi(vals[i] - bf16_f(h));
    }
  }
  // per-lane drive prefetch for step 1 (element r: chain q*4+r, col n0+c16)
  float vnext[4];
  if (MODE != 0) {
#pragma unroll
    for (int r = 0; r < 4; r++) {
      int cg = blk * 16 + q * 4 + r;
      int drow = (MODE == 1) ? 1 : 0;
      vnext[r] = V[((size_t)cg * CLEN + drow) * 256 + n0 + c16];
    }
  }
  __syncthreads();
  for (int s = 1; s <= STEPS; s++) {
    int cur = (s - 1) & 1, nxt = s & 1;
    // MODE 2: flush rows s-4..s-1 (slots row%5) — mod-5 disjoint vs writes
    if (MODE == 2 && s >= 5 && ((s - 1) & 3) == 0) {
      int rbase = s - 4;
      for (int e = t; e < 4096; e += 1024) {
        int slot = e >> 10;
        int rem = e & 1023;
        int c = rem >> 6, qq = (rem & 63) * 4;
        int row = rbase + slot;
        int cg = blk * 16 + c;
        *(float4*)(Out + ((size_t)cg * CLEN + row) * 256 + qq) = *(const float4*)&hist[row % 5][c][qq];
      }
    }
    // drive: consume prefetched, issue next step's loads (hidden under MFMAs)
    float vc[4];
    if (MODE != 0) {
#pragma unroll
      for (int i2 = 0; i2 < 4; i2++) vc[i2] = vnext[i2];
      if (s < STEPS) {
        int drow = (MODE == 1) ? (s + 1) : s;
#pragma unroll
        for (int r = 0; r < 4; r++)
          vnext[r] = V[((size_t)(blk * 16 + q * 4 + r) * CLEN + drow) * 256 + n0 + c16];
      }
    }
    // pin frags: rw asm operand => value must live in VGPRs, reload illegal
#pragma unroll
    for (int kt = 0; kt < 8; kt++) {
      asm volatile("" : "+v"(bh[kt]));
      asm volatile("" : "+v"(bl[kt]));
    }
    float4v aH = {0.f, 0.f, 0.f, 0.f};
    float4v aL = {0.f, 0.f, 0.f, 0.f};
    float4v aC = {0.f, 0.f, 0.f, 0.f};
#pragma unroll
    for (int kt = 0; kt < 8; kt++) {
      short8 ah = *(const short8*)&xh[cur][kt * 4 + q][c16][0];
      short8 al = *(const short8*)&xl[cur][kt * 4 + q][c16][0];
      aH = __builtin_amdgcn_mfma_f32_16x16x32_bf16(ah, bh[kt], aH, 0, 0, 0);
      aL = __builtin_amdgcn_mfma_f32_16x16x32_bf16(al, bh[kt], aL, 0, 0, 0);
      aC = __builtin_amdgcn_mfma_f32_16x16x32_bf16(ah, bl[kt], aC, 0, 0, 0);
    }
    // epilogue: C/D layout chain=(q*4+r), col=c16 (m89-verified)
#pragma unroll
    for (int r = 0; r < 4; r++) {
      int c = q * 4 + r;
      int n = n0 + c16;
      float val = aH[r] + aL[r] + aC[r];
      if (MODE != 0) val += vc[r];
      int cg = blk * 16 + c;
      if (MODE == 2) hist[s % 5][c][n] = val;
      if (MODE == 1 && s == STEPS) Out[(size_t)cg * 256 + n] = val;
      if (MODE == 0 && s == STEPS) {
        ushort_t h2 = bf16_hi(val);
        Out[(size_t)n * 256 + cg] = val;
        OutH[(size_t)n * 256 + cg] = h2;
        OutL[(size_t)n * 256 + cg] = bf16_hi(val - bf16_f(h2));
      }
      ushort_t h = bf16_hi(val);
      xh[nxt][n >> 3][c][n & 7] = h;
      xl[nxt][n >> 3][c][n & 7] = bf16_hi(val - bf16_f(h));
    }
    __syncthreads();
  }
  if (MODE == 2) {   // final rows STEPS-2..STEPS
    for (int e = t; e < 3072; e += 1024) {
      int slot = e >> 10;
      int rem = e & 1023;
      int c = rem >> 6, qq = (rem & 63) * 4;
      int row = (STEPS - 2) + slot;
      int cg = blk * 16 + c;
      *(float4*)(Out + ((size_t)cg * CLEN + row) * 256 + qq) = *(const float4*)&hist[row % 5][c][qq];
    }
  }
}

// ---------------------------------------------------------------------------
// Hermite tap value: row n, k = t*32+c -> {u_n, m_n, u_{n+1}, m_{n+1}}[t][c].
// Row TPTS-1 = 0 (pad).
__device__ __forceinline__ float tap_val(const float* __restrict__ u, int n, int k) {
  if (n >= TPTS - 1) return 0.f;
  int t = k >> 5, c = k & 31;
  if (t == 0) return u[(size_t)n * 32 + c];
  if (t == 2) return u[(size_t)(n + 1) * 32 + c];
  int kk = (t == 1) ? n : n + 1;
  if (kk == 0) return u[32 + c] - u[c];
  if (kk == TPTS - 1) return u[(size_t)(TPTS - 1) * 32 + c] - u[(size_t)(TPTS - 2) * 32 + c];
  return 0.5f * (u[(size_t)(kk + 1) * 32 + c] - u[(size_t)(kk - 1) * 32 + c]);
}

// Drive GEMM on MFMA, 1024 threads: V0[rows g*64..g*64+64)[256] =
// taps[64][128] @ F[128][256], bf16 hi/lo split (taps ~ ah+al, F ~ bh+bl;
// 3 of 4 cross products, fp32 accumulate). 4 groups of 16 rows; per group:
// stage taps to LDS in chain_body's A-frag layout [k>>3][row][k&7]
// (2 taps/thread, packed u32 stores), 12 MFMA per wave. F pre-split to
// Fh/Fl[n][k] (B-frag-ready) by unit_resp. Arena: ah @0 (4KB), al @4K (4KB).
__device__ __forceinline__ void drive_body(char* arena, const float* __restrict__ u,
                                           const ushort_t* __restrict__ Fh,
                                           const ushort_t* __restrict__ Fl,
                                           float* __restrict__ V0, int g) {
  int t = threadIdx.x;
  int w = t >> 6, l = t & 63;
  int q = l >> 4, c16 = l & 15;
  int n0 = w * 16;
  ushort_t (*ah)[16][8] = reinterpret_cast<ushort_t(*)[16][8]>(arena);         // [16][16][8]
  ushort_t (*al)[16][8] = reinterpret_cast<ushort_t(*)[16][8]>(arena + 4096);
  // B-frags: B[k][n] = F[k][n] = Fh/Fl[n*128 + k]; lane needs k=kt*32+q*8+j
  short8 bh[4], bl[4];
#pragma unroll
  for (int kt = 0; kt < 4; kt++) {
    size_t offs = (size_t)(n0 + c16) * 128 + kt * 32 + q * 8;
    bh[kt] = *(const short8*)(Fh + offs);
    bl[kt] = *(const short8*)(Fl + offs);
  }
  int rowbase = g * 64;
  int srow = t >> 6;      // staging row 0..15
  int k0 = l * 2;         // staging k 0..126 (even; k0,k0+1 same 8-group)
  for (int grp = 0; grp < 4; grp++) {
    int rb = rowbase + grp * 16;
    float v0 = tap_val(u, rb + srow, k0);
    float v1 = tap_val(u, rb + srow, k0 + 1);
    ushort_t h0 = bf16_hi(v0), h1 = bf16_hi(v1);
    ushort_t lo0 = bf16_hi(v0 - bf16_f(h0)), lo1 = bf16_hi(v1 - bf16_f(h1));
    *(unsigned*)&ah[k0 >> 3][srow][k0 & 7] = (unsigned)h0 | ((unsigned)h1 << 16);
    *(unsigned*)&al[k0 >> 3][srow][k0 & 7] = (unsigned)lo0 | ((unsigned)lo1 << 16);
    __syncthreads();
    float4v aH = {0.f, 0.f, 0.f, 0.f};
    float4v aL = {0.f, 0.f, 0.f, 0.f};
    float4v aC = {0.f, 0.f, 0.f, 0.f};
#pragma unroll
    for (int kt = 0; kt < 4; kt++) {
      short8 a_h = *(const short8*)&ah[kt * 4 + q][c16][0];
      short8 a_l = *(const short8*)&al[kt * 4 + q][c16][0];
      aH = __builtin_amdgcn_mfma_f32_16x16x32_bf16(a_h, bh[kt], aH, 0, 0, 0);
      aL = __builtin_amdgcn_mfma_f32_16x16x32_bf16(a_l, bh[kt], aL, 0, 0, 0);
      aC = __builtin_amdgcn_mfma_f32_16x16x32_bf16(a_h, bl[kt], aC, 0, 0, 0);
    }
    // C/D: row = q*4+r, col = c16 (same mapping as chain_body epilogue)
#pragma unroll
    for (int r = 0; r < 4; r++) {
      int row = rb + q * 4 + r;
      V0[(size_t)row * 256 + n0 + c16] = aH[r] + aL[r] + aC[r];
    }
    __syncthreads();
  }
}

// ---------------------------------------------------------------------------
// Fused kernels (disjoint block ranges; no cross-block dependencies in-kernel)
__global__ __launch_bounds__(1024, 4) void pow8_gemm(const ushort_t* Rh, const ushort_t* Rl,
                                                     float* PowFp, ushort_t* R8h, ushort_t* R8l,
                                                     const float* u, const ushort_t* Fh,
                                                     const ushort_t* Fl, float* V0) {
  __shared__ __attribute__((aligned(16))) char arena[49152];
  int blk = blockIdx.x;
  if (blk < 16)
    chain_body<0, 8>(arena, Rh, Rl, nullptr, nullptr, PowFp, R8h, R8l, blk);
  else
    drive_body(arena, u, Fh, Fl, V0, blk - 16);
}

__global__ __launch_bounds__(1024, 4) void pow64_reduce0(const ushort_t* R8h, const ushort_t* R8l,
                                                         float* PowFp, ushort_t* R64h, ushort_t* R64l,
                                                         const ushort_t* Rh, const ushort_t* Rl,
                                                         const float* V0, float* V1) {
  __shared__ __attribute__((aligned(16))) char arena[49152];
  int blk = blockIdx.x;
  if (blk < 16)
    chain_body<0, 8>(arena, R8h, R8l, nullptr, nullptr, PowFp, R64h, R64l, blk);
  else
    chain_body<1, 8>(arena, Rh, Rl, nullptr, V0, V1, nullptr, nullptr, blk - 16);
}

__global__ __launch_bounds__(1024, 4) void pow512_reduce1(const ushort_t* R64h, const ushort_t* R64l,
                                                          float* R512fp, ushort_t* R512h, ushort_t* R512l,
                                                          const ushort_t* R8h, const ushort_t* R8l,
                                                          const float* V1, float* V2) {
  __shared__ __attribute__((aligned(16))) char arena[49152];
  int blk = blockIdx.x;
  if (blk < 16)
    chain_body<0, 8>(arena, R64h, R64l, nullptr, nullptr, R512fp, R512h, R512l, blk);
  else
    chain_body<1, 8>(arena, R8h, R8l, nullptr, V1, V2, nullptr, nullptr, blk - 16);
}

__global__ __launch_bounds__(1024, 4) void reduce2_k(const ushort_t* R64h, const ushort_t* R64l,
                                                     const float* V2, float* V3) {
  __shared__ __attribute__((aligned(16))) char arena[49152];
  chain_body<1, 8>(arena, R64h, R64l, nullptr, V2, V3, nullptr, nullptr, blockIdx.x);
}

__global__ __launch_bounds__(1024, 4) void expand2_k(const ushort_t* R64h, const ushort_t* R64l,
                                                     const float* X3, const float* V2, float* X2) {
  __shared__ __attribute__((aligned(16))) char arena[114688];
  chain_body<2, 8>(arena, R64h, R64l, X3, V2, X2, nullptr, nullptr, blockIdx.x);
}

__global__ __launch_bounds__(1024, 4) void expand1_k(const ushort_t* R8h, const ushort_t* R8l,
                                                     const float* X2, const float* V1, float* X1) {
  __shared__ __attribute__((aligned(16))) char arena[114688];
  chain_body<2, 8>(arena, R8h, R8l, X2, V1, X1, nullptr, nullptr, blockIdx.x);
}

__global__ __launch_bounds__(1024, 4) void expand0_k(const ushort_t* Rh, const ushort_t* Rl,
                                                     const float* X1, const float* V0, float* xout) {
  __shared__ __attribute__((aligned(16))) char arena[114688];
  chain_body<2, 8>(arena, Rh, Rl, X1, V0, xout, nullptr, nullptr, blockIdx.x);
}

// ---------------------------------------------------------------------------
// y = x @ C^T + u @ D^T. Register-tiled 4x4 (v5-verified). 256 blocks x 256
// thr; thread (rt,ct) computes rows n0+rt*4+0..3 x cols ct*4+0..3. C/D stored
// TRANSPOSED in LDS (conflict-free); x read straight from global (L2/L3).
__global__ __launch_bounds__(256) void y_kernel(const float* __restrict__ x, const float* __restrict__ u,
                                                const float* __restrict__ Cm, const float* __restrict__ Dm,
                                                float* __restrict__ y) {
  __shared__ float CsT[256][36];
  __shared__ float DsT[32][36];
  int tid = threadIdx.x;
  for (int k = tid; k < 8192; k += 256) CsT[k & 255][k >> 8] = Cm[k];
  for (int k = tid; k < 1024; k += 256) DsT[k & 31][k >> 5] = Dm[k];
  __syncthreads();
  int rt = tid >> 3, ct = tid & 7;
  int n0 = blockIdx.x * 128 + rt * 4;
  int o0 = ct * 4;
  float acc[4][4] = {{0.f}};
#pragma unroll 4
  for (int i = 0; i < 256; i += 4) {
    float4 cv0 = *(const float4*)&CsT[i + 0][o0];
    float4 cv1 = *(const float4*)&CsT[i + 1][o0];
    float4 cv2 = *(const float4*)&CsT[i + 2][o0];
    float4 cv3 = *(const float4*)&CsT[i + 3][o0];
#pragma unroll
    for (int r = 0; r < 4; r++) {
      float4 xv = *(const float4*)(x + (size_t)(n0 + r) * 256 + i);
      acc[r][0] += xv.x * cv0.x + xv.y * cv1.x + xv.z * cv2.x + xv.w * cv3.x;
      acc[r][1] += xv.x * cv0.y + xv.y * cv1.y + xv.z * cv2.y + xv.w * cv3.y;
      acc[r][2] += xv.x * cv0.z + xv.y * cv1.z + xv.z * cv2.z + xv.w * cv3.z;
      acc[r][3] += xv.x * cv0.w + xv.y * cv1.w + xv.z * cv2.w + xv.w * cv3.w;
    }
  }
#pragma unroll
  for (int i = 0; i < 32; i += 4) {
    float4 dv0 = *(const float4*)&DsT[i + 0][o0];
    float4 dv1 = *(const float4*)&DsT[i + 1][o0];
    float4 dv2 = *(const float4*)&DsT[i + 2][o0];
    float4 dv3 = *(const float4*)&DsT[i + 3][o0];
#pragma unroll
    for (int r = 0; r < 4; r++) {
      float4 uv = *(const float4*)(u + (size_t)(n0 + r) * 32 + i);
      acc[r][0] += uv.x * dv0.x + uv.y * dv1.x + uv.z * dv2.x + uv.w * dv3.x;
      acc[r][1] += uv.x * dv0.y + uv.y * dv1.y + uv.z * dv2.y + uv.w * dv3.y;
      acc[r][2] += uv.x * dv0.z + uv.y * dv1.z + uv.z * dv2.z + uv.w * dv3.z;
      acc[r][3] += uv.x * dv0.w + uv.y * dv1.w + uv.z * dv2.w + uv.w * dv3.w;
    }
  }
#pragma unroll
  for (int r = 0; r < 4; r++)
    *(float4*)(y + (size_t)(n0 + r) * 32 + o0) =
        make_float4(acc[r][0], acc[r][1], acc[r][2], acc[r][3]);
}

// ---------------------------------------------------------------------------
// AT = A^T (256x256)
__global__ __launch_bounds__(256) void transpose_at(const float* __restrict__ A, float* __restrict__ AT) {
  __shared__ float tile[64][65];
  int bx = blockIdx.x & 3, by = blockIdx.x >> 2;
  int r0 = by * 64, c0 = bx * 64;
  int t = threadIdx.x;
  int lr = t >> 4, lc = (t & 15) * 4;
  for (int rr = lr; rr < 64; rr += 16) {
    float4 v = *(const float4*)(A + (size_t)(r0 + rr) * 256 + c0 + lc);
    tile[rr][lc + 0] = v.x; tile[rr][lc + 1] = v.y; tile[rr][lc + 2] = v.z; tile[rr][lc + 3] = v.w;
  }
  __syncthreads();
  for (int rr = lr; rr < 64; rr += 16) {
    float4 v = make_float4(tile[lc + 0][rr], tile[lc + 1][rr], tile[lc + 2][rr], tile[lc + 3][rr]);
    *(float4*)(AT + (size_t)(c0 + rr) * 256 + r0 + lc) = v;
  }
}

// Unit responses through one Dopri5 step: cols 0..255 -> R fp32 + bf16 hi/lo
// split; cols 256..383 -> Hermite-folded tap matrices, bf16 hi/lo split,
// stored TRANSPOSED as Fh/Fl[n][k] (B-frag-ready for drive_body).
// 1024 threads = 4 j-groups x 256 rows; 4-way split-K with LDS reduce.
__global__ __launch_bounds__(1024) void unit_resp(const float* __restrict__ AT,
                                                  const float* __restrict__ Bm,
                                                  float* __restrict__ Rout,
                                                  ushort_t* __restrict__ Rh,
                                                  ushort_t* __restrict__ Rl,
                                                  ushort_t* __restrict__ Fh,
                                                  ushort_t* __restrict__ Fl) {
  int blk = blockIdx.x;
  int tid = threadIdx.x;
  int jg = tid >> 8;   // j-group 0..3, also the owned column index cc
  int i = tid & 255;   // output row
  int cc = jg;
  int col = blk * 4 + cc;

  __shared__ float xs4[256][4];
  __shared__ float4 part[4][256];

  const float AA[6][5] = {
      {0.f, 0.f, 0.f, 0.f, 0.f},
      {0.2f, 0.f, 0.f, 0.f, 0.f},
      {3.f / 40.f, 9.f / 40.f, 0.f, 0.f, 0.f},
      {44.f / 45.f, -56.f / 15.f, 32.f / 9.f, 0.f, 0.f},
      {19372.f / 6561.f, -25360.f / 2187.f, 64448.f / 6561.f, -212.f / 729.f, 0.f},
      {9017.f / 3168.f, -355.f / 33.f, 46732.f / 5247.f, 49.f / 176.f, -5103.f / 18656.f}};
  const float BB[6] = {35.f / 384.f, 0.f, 500.f / 1113.f, 125.f / 192.f, -2187.f / 6784.f, 11.f / 84.f};
  const float sv[6] = {0.f, 0.2f, 0.3f, 0.8f, 8.f / 9.f, 1.f};
  float Hm[6][4];
#pragma unroll
  for (int s = 0; s < 6; s++) {
    float ss = sv[s], s2 = ss * ss, s3 = s2 * ss;
    Hm[s][0] = 2.f * s3 - 3.f * s2 + 1.f;
    Hm[s][1] = s3 - 2.f * s2 + ss;
    Hm[s][2] = -2.f * s3 + 3.f * s2;
    Hm[s][3] = s3 - s2;
  }

  // owned-column metadata
  int isF, tt;
  float brow, xc;
  if (col < 256) {
    isF = 0; tt = 0; brow = 0.f;
    xc = (i == col) ? 1.f : 0.f;
  } else {
    isF = 1; xc = 0.f;
    int f = col - 256;
    tt = f >> 5;
    brow = Bm[i * 32 + (f & 31)];
  }
  float bh[6];
#pragma unroll
  for (int s = 0; s < 6; s++) {
    float hv = (tt == 0) ? Hm[s][0] : ((tt == 1) ? Hm[s][1] : ((tt == 2) ? Hm[s][2] : Hm[s][3]));
    bh[s] = isF ? hv * brow : 0.f;
  }

  float kreg[6];
#pragma unroll
  for (int s = 0; s < 6; s++) kreg[s] = 0.f;

  int j0 = jg * 64;
#pragma unroll 1
  for (int s = 0; s < 6; s++) {
    float xsv = xc;
#pragma unroll
    for (int j = 0; j < 5; j++)
      if (j < s) xsv += AA[s][j] * kreg[j];
    xs4[i][cc] = xsv;
    __syncthreads();
    float acx = 0.f, acy = 0.f, acz = 0.f, acw = 0.f;
#pragma unroll 8
    for (int jj = 0; jj < 64; jj++) {
      int j = j0 + jj;
      float a = AT[(size_t)j * 256 + i];
      float4 xv = *(const float4*)xs4[j];
      acx += a * xv.x;
      acy += a * xv.y;
      acz += a * xv.z;
      acw += a * xv.w;
    }
    part[jg][i] = make_float4(acx, acy, acz, acw);
    __syncthreads();
    float k = bh[s];
#pragma unroll
    for (int g = 0; g < 4; g++) {
      const float* p = (const float*)&part[g][i];
      k += p[cc];
    }
    kreg[s] = k;
  }

  float o = xc;
#pragma unroll
  for (int s = 0; s < 6; s++) o += BB[s] * kreg[s];
  if (!isF) {
    Rout[(size_t)i * 256 + col] = o;
    ushort_t h = bf16_hi(o);
    Rh[(size_t)i * 256 + col] = h;
    Rl[(size_t)i * 256 + col] = bf16_hi(o - bf16_f(h));
  } else {
    int f = col - 256;
    ushort_t h = bf16_hi(o);
    Fh[(size_t)i * 128 + f] = h;
    Fl[(size_t)i * 128 + f] = bf16_hi(o - bf16_f(h));
  }
}

// Top-level starts at stride 512: 64 blocks. X3[k] = x_{512k}.
// 3-term truncated recurrence (exact k<=2; k>=3 drops ||R^1536|| ~ 5e-7).
__global__ __launch_bounds__(256) void top_scan(const float* __restrict__ V3, const float* __restrict__ x0,
                                                const float* __restrict__ R512, float* __restrict__ X3) {
  int k = blockIdx.x, i = threadIdx.x;
  if (k == 0) { X3[i] = x0[i]; return; }
  __shared__ float va[256];
  __shared__ float inner[256];
  if (k == 1) {
    inner[i] = x0[i];
  } else {
    const float* vecA = (k == 2) ? x0 : (V3 + (size_t)(k - 3) * 256);
    va[i] = vecA[i];
    __syncthreads();
    float acc = V3[(size_t)(k - 2) * 256 + i];
    const float* rr = R512 + (size_t)i * 256;
    for (int j = 0; j < 256; j += 4) {
      float4 rv = *(const float4*)(rr + j);
      acc += rv.x * va[j] + rv.y * va[j + 1] + rv.z * va[j + 2] + rv.w * va[j + 3];
    }
    inner[i] = acc;
  }
  __syncthreads();
  float acc2 = V3[(size_t)(k - 1) * 256 + i];
  const float* rr2 = R512 + (size_t)i * 256;
  for (int j = 0; j < 256; j += 4) {
    float4 rv = *(const float4*)(rr2 + j);
    acc2 += rv.x * inner[j] + rv.y * inner[j + 1] + rv.z * inner[j + 2] + rv.w * inner[j + 3];
  }
  X3[(size_t)k * 256 + i] = acc2;
}

extern "C" void kernel_launch(void* const* d_in, const int* in_sizes, int n_in,
                              void* d_out, int out_size, void* d_ws, size_t ws_size,
                              hipStream_t stream) {
  const float* u  = (const float*)d_in[1];
  const float* x0 = (const float*)d_in[2];
  const float* A  = (const float*)d_in[3];
  const float* Bm = (const float*)d_in[4];
  const float* Cm = (const float*)d_in[5];
  const float* Dm = (const float*)d_in[6];
  float* xout = (float*)d_out;                       // [32768][256]
  float* yout = xout + (size_t)TPTS * 256;           // [32768][32]

  char* wsb = (char*)d_ws;
  size_t off = 0;
  auto alloc = [&](size_t bytes) -> void* {
    void* p = (void*)(wsb + off);
    off = (off + bytes + 255) & ~(size_t)255;
    return p;
  };
  float*    Rfp    = (float*)alloc(65536 * 4);
  ushort_t* Rh     = (ushort_t*)alloc(65536 * 2);
  ushort_t* Rl     = (ushort_t*)alloc(65536 * 2);
  float*    PowFp  = (float*)alloc(65536 * 4);       // scratch fp out for R^8/R^64
  ushort_t* R8h    = (ushort_t*)alloc(65536 * 2);
  ushort_t* R8l    = (ushort_t*)alloc(65536 * 2);
  ushort_t* R64h   = (ushort_t*)alloc(65536 * 2);
  ushort_t* R64l   = (ushort_t*)alloc(65536 * 2);
  float*    R512fp = (float*)alloc(65536 * 4);
  ushort_t* R512h  = (ushort_t*)alloc(65536 * 2);
  ushort_t* R512l  = (ushort_t*)alloc(65536 * 2);
  float*    ATm    = (float*)alloc(65536 * 4);
  ushort_t* Fh     = (ushort_t*)alloc(256 * 128 * 2);
  ushort_t* Fl     = (ushort_t*)alloc(256 * 128 * 2);
  float*    V0     = (float*)alloc((size_t)TPTS * 256 * 4);
  float*    V1     = (float*)alloc(4096 * 256 * 4);
  float*    V2     = (float*)alloc(512 * 256 * 4);
  float*    V3     = (float*)alloc(64 * 256 * 4);
  float*    X3     = (float*)alloc(64 * 256 * 4);
  float*    X2     = (float*)alloc(512 * 256 * 4);
  float*    X1     = (float*)alloc(4096 * 256 * 4);
  (void)ws_size; (void)in_sizes; (void)n_in; (void)out_size;

  // 1. A^T; unit responses -> R (fp32 + hi/lo) and Fh/Fl
  transpose_at<<<dim3(16), dim3(256), 0, stream>>>(A, ATm);
  unit_resp<<<dim3(96), dim3(1024), 0, stream>>>(ATm, Bm, Rfp, Rh, Rl, Fh, Fl);

  // 2. pow8 (16 blk) || MFMA drive GEMM (512 blk) — independent given unit_resp
  pow8_gemm<<<dim3(528), dim3(1024), 0, stream>>>(Rh, Rl, PowFp, R8h, R8l, u, Fh, Fl, V0);

  // 3. pow64 (16) || reduce0 (256)
  pow64_reduce0<<<dim3(272), dim3(1024), 0, stream>>>(R8h, R8l, PowFp, R64h, R64l, Rh, Rl, V0, V1);

  // 4. pow512 (16) || reduce1 (32)
  pow512_reduce1<<<dim3(48), dim3(1024), 0, stream>>>(R64h, R64l, R512fp, R512h, R512l, R8h, R8l, V1, V2);

  // 5. reduce2, top starts, expand down
  reduce2_k<<<dim3(4), dim3(1024), 0, stream>>>(R64h, R64l, V2, V3);
  top_scan<<<dim3(64), dim3(256), 0, stream>>>(V3, x0, R512fp, X3);
  expand2_k<<<dim3(4), dim3(1024), 0, stream>>>(R64h, R64l, X3, V2, X2);
  expand1_k<<<dim3(32), dim3(1024), 0, stream>>>(R8h, R8l, X2, V1, X1);

  // 6. expand0, then y (separate launches — fused version carried +64MB
  //    structural excess traffic, r8/r9 counters)
  expand0_k<<<dim3(256), dim3(1024), 0, stream>>>(Rh, Rl, X1, V0, xout);
  y_kernel<<<dim3(256), dim3(256), 0, stream>>>(xout, u, Cm, Dm, yout);
}